// Round 10
// baseline (1585.547 us; speedup 1.0000x reference)
//
#include <hip/hip_runtime.h>
#include <cstddef>

#define DEVINF __builtin_inff()

typedef __attribute__((ext_vector_type(8))) short bf16x8;
typedef __attribute__((ext_vector_type(4))) float f32x4;
typedef __attribute__((ext_vector_type(2))) float f32x2;

__device__ __forceinline__ unsigned short f2bf(float x) {
  unsigned u = __float_as_uint(x);
  return (unsigned short)((u + 0x7fff + ((u >> 16) & 1)) >> 16);
}
__device__ __forceinline__ float bf2f(unsigned short h) {
  return __uint_as_float(((unsigned)h) << 16);
}
__device__ __forceinline__ void split_bf(float x, unsigned short& hi, unsigned short& lo) {
  hi = f2bf(x);
  lo = f2bf(x - bf2f(hi));
}

// ---------------------------------------------------------------------------
// FPS cooperative step: each wave updates its own point range (PPLH f32x2 per
// lane), reduces to a per-wave winner key via DPP; caller exchanges 4 keys
// through LDS. Key = (val_bits<<32)|~idx: u64 max == (max val, lowest idx)
// == numpy first-max (distances >= 0 so bit-ordering is valid).
// ---------------------------------------------------------------------------
#define FPS_RED_LEVEL(CTRL)                                                      \
  {                                                                              \
    int th = __builtin_amdgcn_update_dpp((int)hi, (int)hi, CTRL, 0xf, 0xf, false); \
    int tl = __builtin_amdgcn_update_dpp((int)lo, (int)lo, CTRL, 0xf, 0xf, false); \
    bool take = ((unsigned)th > hi) || (((unsigned)th == hi) && ((unsigned)tl > lo)); \
    hi = take ? (unsigned)th : hi;                                               \
    lo = take ? (unsigned)tl : lo;                                               \
  }

template <int PPLH, int NCH>
__device__ __forceinline__ unsigned long long fps_wave_step(
    f32x2* qx, f32x2* qy, f32x2* qz, f32x2* d, float lx, float ly, float lz,
    int lane, int ibase) {
#pragma clang fp contract(off)
  const int CH = PPLH / NCH;
  float bv[NCH];
  int bi[NCH];
#pragma unroll
  for (int c = 0; c < NCH; ++c) { bv[c] = -DEVINF; bi[c] = 0x7fffffff; }
  f32x2 lxv = {lx, lx}, lyv = {ly, ly}, lzv = {lz, lz};
#pragma unroll
  for (int h = 0; h < PPLH; ++h) {
    const int c = h / CH;
    f32x2 dx = qx[h] - lxv, dy = qy[h] - lyv, dz = qz[h] - lzv;
    f32x2 t0 = dx * dx, t1 = dy * dy, t2 = dz * dz;
    f32x2 d2 = (t0 + t1) + t2;
    f32x2 dn;
    dn.x = fminf(d[h].x, d2.x);
    dn.y = fminf(d[h].y, d2.y);
    d[h] = dn;
    int i0 = ibase + (2 * h) * 64 + lane;
    if (dn.x > bv[c]) { bv[c] = dn.x; bi[c] = i0; }
    if (dn.y > bv[c]) { bv[c] = dn.y; bi[c] = i0 + 64; }
  }
  unsigned hi, lo;
  if (NCH == 4) {
    unsigned h0 = __float_as_uint(bv[0]), l0 = ~(unsigned)bi[0];
    unsigned h1 = __float_as_uint(bv[1]), l1 = ~(unsigned)bi[1];
    unsigned h2 = __float_as_uint(bv[2]), l2 = ~(unsigned)bi[2];
    unsigned h3 = __float_as_uint(bv[3]), l3 = ~(unsigned)bi[3];
    bool t01 = (h1 > h0) || ((h1 == h0) && (l1 > l0));
    unsigned ha = t01 ? h1 : h0, la = t01 ? l1 : l0;
    bool t23 = (h3 > h2) || ((h3 == h2) && (l3 > l2));
    unsigned hb = t23 ? h3 : h2, lb = t23 ? l3 : l2;
    bool tab = (hb > ha) || ((hb == ha) && (lb > la));
    hi = tab ? hb : ha;
    lo = tab ? lb : la;
  } else {
    const int c1 = (NCH > 1) ? 1 : 0;
    unsigned h0 = __float_as_uint(bv[0]), l0 = ~(unsigned)bi[0];
    unsigned h1 = __float_as_uint(bv[c1]), l1 = ~(unsigned)bi[c1];
    bool t01 = (h1 > h0) || ((h1 == h0) && (l1 > l0));
    hi = t01 ? h1 : h0;
    lo = t01 ? l1 : l0;
  }
  FPS_RED_LEVEL(0x111)  // row_shr:1
  FPS_RED_LEVEL(0x112)  // row_shr:2
  FPS_RED_LEVEL(0x114)  // row_shr:4
  FPS_RED_LEVEL(0x118)  // row_shr:8
  FPS_RED_LEVEL(0x142)  // row_bcast:15
  FPS_RED_LEVEL(0x143)  // row_bcast:31
  return (((unsigned long long)hi) << 32) | lo;  // valid on lane 63
}

// ---------------------------------------------------------------------------
// prep jobs table (weight transposes fused into fps launch, 256-granular).
// ---------------------------------------------------------------------------
struct PrepJobs {
  const float* src[9];
  unsigned short* hi[9];
  unsigned short* lo[9];
  int K[9], N[9], rl[9];
  int blk0[10];
};

// ---------------------------------------------------------------------------
// fps kernel (blocks 0..15): fps1 (2048->1024) then fps2 (1024->256) back to
// back in the SAME block — fps2's input (carr) is already in LDS, and with
// only 16 blocks + short prep resident, the fps2 serial chain runs
// UNCONTENDED (it previously shared CUs with sa1's MFMA blocks and its
// per-step latency blew up 3-4x). blocks 16..: weight prep.
// ---------------------------------------------------------------------------
__global__ __launch_bounds__(256, 1) void fps_prep_kernel(
    const float* __restrict__ pos, float* __restrict__ p1,
    float* __restrict__ p2, PrepJobs jb) {
#pragma clang fp contract(off)
  const int tid = threadIdx.x;
  if (blockIdx.x >= 16) {
    int blk = blockIdx.x - 16;
    int j = 0;
#pragma unroll
    for (int t = 1; t < 9; ++t)
      if (blk >= jb.blk0[t]) j = t;
    int idx = (blk - jb.blk0[j]) * 256 + tid;
    int rl = jb.rl[j], N = jb.N[j], K = jb.K[j];
    if (idx >= N * rl) return;
    int n = idx / rl, k = idx - n * rl;
    float v = (k < K) ? jb.src[j][(size_t)k * N + n] : 0.f;
    unsigned short h, l;
    split_bf(v, h, l);
    jb.hi[j][idx] = h;
    jb.lo[j][idx] = l;
    return;
  }
  const int b = blockIdx.x;
  const int w = tid >> 6, lane = tid & 63;
  __shared__ __align__(16) float4 p4[2048];
  __shared__ __align__(16) float4 carr[1024];
  __shared__ unsigned long long kv[2][4];
  // ---------------- fps1: 2048 -> 1024 ----------------
  {
    f32x2 qx[4], qy[4], qz[4], d[4];
    const int ibase = w * 512;
#pragma unroll
    for (int h = 0; h < 4; ++h) {
      int i0 = ibase + (2 * h) * 64 + lane, i1 = i0 + 64;
      const float* a = pos + ((size_t)b * 2048 + i0) * 3;
      const float* c = pos + ((size_t)b * 2048 + i1) * 3;
      float x0 = a[0], y0 = a[1], z0 = a[2];
      float x1 = c[0], y1 = c[1], z1 = c[2];
      qx[h].x = x0; qx[h].y = x1;
      qy[h].x = y0; qy[h].y = y1;
      qz[h].x = z0; qz[h].y = z1;
      d[h].x = DEVINF; d[h].y = DEVINF;
      p4[i0] = float4{x0, y0, z0, 0.f};
      p4[i1] = float4{x1, y1, z1, 0.f};
    }
    __syncthreads();
    int last = 0;
    for (int s = 0; s < 1024; ++s) {
      float4 c4 = p4[last];
      if (tid == 0) carr[s] = c4;
      unsigned long long k =
          fps_wave_step<4, 4>(qx, qy, qz, d, c4.x, c4.y, c4.z, lane, ibase);
      if (lane == 63) kv[s & 1][w] = k;
      __syncthreads();
      unsigned long long k0 = kv[s & 1][0], k1 = kv[s & 1][1];
      unsigned long long k2 = kv[s & 1][2], k3 = kv[s & 1][3];
      unsigned long long ka = k0 > k1 ? k0 : k1;
      unsigned long long kb = k2 > k3 ? k2 : k3;
      unsigned long long kk = ka > kb ? ka : kb;
      last = (int)~(unsigned)kk;
    }
    for (int i = tid; i < 1024; i += 256) {
      float4 c = carr[i];
      p1[((size_t)b * 1024 + i) * 3 + 0] = c.x;
      p1[((size_t)b * 1024 + i) * 3 + 1] = c.y;
      p1[((size_t)b * 1024 + i) * 3 + 2] = c.z;
    }
  }
  __syncthreads();
  // ---------------- fps2: 1024 (carr) -> 256 ----------------
  {
    float4* carr2 = p4;  // p4 dead after fps1; reuse first 256 entries
    f32x2 qx[2], qy[2], qz[2], d[2];
    const int ibase = w * 256;
#pragma unroll
    for (int h = 0; h < 2; ++h) {
      int i0 = ibase + (2 * h) * 64 + lane, i1 = i0 + 64;
      float4 a = carr[i0], c = carr[i1];
      qx[h].x = a.x; qx[h].y = c.x;
      qy[h].x = a.y; qy[h].y = c.y;
      qz[h].x = a.z; qz[h].y = c.z;
      d[h].x = DEVINF; d[h].y = DEVINF;
    }
    int last = 0;
    for (int s = 0; s < 256; ++s) {
      float4 c4 = carr[last];
      if (tid == 0) carr2[s] = c4;
      unsigned long long k =
          fps_wave_step<2, 2>(qx, qy, qz, d, c4.x, c4.y, c4.z, lane, ibase);
      if (lane == 63) kv[s & 1][w] = k;
      __syncthreads();
      unsigned long long k0 = kv[s & 1][0], k1 = kv[s & 1][1];
      unsigned long long k2 = kv[s & 1][2], k3 = kv[s & 1][3];
      unsigned long long ka = k0 > k1 ? k0 : k1;
      unsigned long long kb = k2 > k3 ? k2 : k3;
      unsigned long long kk = ka > kb ? ka : kb;
      last = (int)~(unsigned)kk;
    }
    if (tid < 256) {
      float4 c = carr2[tid];
      p2[((size_t)b * 256 + tid) * 3 + 0] = c.x;
      p2[((size_t)b * 256 + tid) * 3 + 1] = c.y;
      p2[((size_t)b * 256 + tid) * 3 + 2] = c.z;
    }
  }
}

// ---------------------------------------------------------------------------
// MFMA building blocks (B fragments loaded once per 12 MFMAs).
// ---------------------------------------------------------------------------
template <int KS, int T>
__device__ __forceinline__ void mfma_allm(
    const unsigned short* __restrict__ inHi, const unsigned short* __restrict__ inLo,
    int sIn, const unsigned short* __restrict__ wHi,
    const unsigned short* __restrict__ wLo, int rl, const float* __restrict__ bias,
    int n0, int lane, f32x4 acc[4][T]) {
  const int col = lane & 15, quad = lane >> 4;
#pragma unroll
  for (int t = 0; t < T; ++t) {
    float bv = bias[n0 + t * 16 + col];
#pragma unroll
    for (int mt = 0; mt < 4; ++mt) {
      acc[mt][t].x = bv; acc[mt][t].y = bv; acc[mt][t].z = bv; acc[mt][t].w = bv;
    }
  }
#pragma unroll 1
  for (int ks = 0; ks < KS; ++ks) {
    bf16x8 ah[4], al[4];
#pragma unroll
    for (int mt = 0; mt < 4; ++mt) {
      int aoff = (mt * 16 + col) * sIn + ks * 32 + quad * 8;
      ah[mt] = *(const bf16x8*)(inHi + aoff);
      al[mt] = *(const bf16x8*)(inLo + aoff);
    }
#pragma unroll
    for (int t = 0; t < T; ++t) {
      size_t boff = (size_t)(n0 + t * 16 + col) * rl + ks * 32 + quad * 8;
      bf16x8 bh = *(const bf16x8*)(wHi + boff);
      bf16x8 bl = *(const bf16x8*)(wLo + boff);
#pragma unroll
      for (int mt = 0; mt < 4; ++mt) {
        acc[mt][t] = __builtin_amdgcn_mfma_f32_16x16x32_bf16(ah[mt], bh, acc[mt][t], 0, 0, 0);
        acc[mt][t] = __builtin_amdgcn_mfma_f32_16x16x32_bf16(ah[mt], bl, acc[mt][t], 0, 0, 0);
        acc[mt][t] = __builtin_amdgcn_mfma_f32_16x16x32_bf16(al[mt], bh, acc[mt][t], 0, 0, 0);
      }
    }
  }
}

template <int T>
__device__ __forceinline__ void store_allm(const f32x4 acc[4][T], int n0,
                                           unsigned short* outHi,
                                           unsigned short* outLo, int sOut,
                                           int lane) {
  const int col = lane & 15, quad = lane >> 4;
#pragma unroll
  for (int mt = 0; mt < 4; ++mt)
#pragma unroll
    for (int t = 0; t < T; ++t)
#pragma unroll
      for (int r = 0; r < 4; ++r) {
        int edge = mt * 16 + quad * 4 + r;
        float v = fmaxf(acc[mt][t][r], 0.f);
        unsigned short h, l;
        split_bf(v, h, l);
        outHi[edge * sOut + n0 + t * 16 + col] = h;
        outLo[edge * sOut + n0 + t * 16 + col] = l;
      }
}

template <int T>
__device__ __forceinline__ void outpool_allm(const f32x4 acc[4][T], int n0,
                                             float* __restrict__ outp, int nvalid,
                                             int lane) {
  const int col = lane & 15, quad = lane >> 4;
#pragma unroll
  for (int t = 0; t < T; ++t) {
    float m = -DEVINF;
#pragma unroll
    for (int mt = 0; mt < 4; ++mt)
#pragma unroll
      for (int r = 0; r < 4; ++r) {
        int edge = mt * 16 + quad * 4 + r;
        float v = fmaxf(acc[mt][t][r], 0.f);
        if (edge >= nvalid) v = -DEVINF;
        m = fmaxf(m, v);
      }
    m = fmaxf(m, __shfl_xor(m, 16, 64));
    m = fmaxf(m, __shfl_xor(m, 32, 64));
    if (quad == 0) outp[n0 + t * 16 + col] = m;
  }
}

// single-m-tile variants (gsa)
template <int KS, int T>
__device__ __forceinline__ void mfma_1m(
    const unsigned short* __restrict__ inHi, const unsigned short* __restrict__ inLo,
    int sIn, const unsigned short* __restrict__ wHi,
    const unsigned short* __restrict__ wLo, int rl, const float* __restrict__ bias,
    int n0, int lane, f32x4 acc[T]) {
  const int col = lane & 15, quad = lane >> 4;
#pragma unroll
  for (int t = 0; t < T; ++t) {
    float bv = bias[n0 + t * 16 + col];
    acc[t].x = bv; acc[t].y = bv; acc[t].z = bv; acc[t].w = bv;
  }
#pragma unroll 1
  for (int ks = 0; ks < KS; ++ks) {
    int aoff = col * sIn + ks * 32 + quad * 8;
    bf16x8 ah = *(const bf16x8*)(inHi + aoff);
    bf16x8 al = *(const bf16x8*)(inLo + aoff);
#pragma unroll
    for (int t = 0; t < T; ++t) {
      size_t boff = (size_t)(n0 + t * 16 + col) * rl + ks * 32 + quad * 8;
      bf16x8 bh = *(const bf16x8*)(wHi + boff);
      bf16x8 bl = *(const bf16x8*)(wLo + boff);
      acc[t] = __builtin_amdgcn_mfma_f32_16x16x32_bf16(ah, bh, acc[t], 0, 0, 0);
      acc[t] = __builtin_amdgcn_mfma_f32_16x16x32_bf16(ah, bl, acc[t], 0, 0, 0);
      acc[t] = __builtin_amdgcn_mfma_f32_16x16x32_bf16(al, bh, acc[t], 0, 0, 0);
    }
  }
}

template <int T>
__device__ __forceinline__ void store_1m(const f32x4 acc[T], int n0,
                                         unsigned short* outHi,
                                         unsigned short* outLo, int sOut, int lane) {
  const int col = lane & 15, quad = lane >> 4;
#pragma unroll
  for (int t = 0; t < T; ++t)
#pragma unroll
    for (int r = 0; r < 4; ++r) {
      int p = quad * 4 + r;
      float v = fmaxf(acc[t][r], 0.f);
      unsigned short h, l;
      split_bf(v, h, l);
      outHi[p * sOut + n0 + t * 16 + col] = h;
      outLo[p * sOut + n0 + t * 16 + col] = l;
    }
}

// ---------------------------------------------------------------------------
// SA1 (MFMA, wave=n-slice): register-mask ball query + MLP 12->64->64->128 +
// maxpool. One center per block, 16384 blocks (fps2 no longer embedded).
// ---------------------------------------------------------------------------
__global__ __launch_bounds__(256, 4) void sa1_kernel(
    const float* __restrict__ x,    // [16][2048][9]
    const float* __restrict__ pos,  // [16][2048][3]
    const float* __restrict__ ctr,  // p1: [16][1024][3]
    const unsigned short* __restrict__ w1h, const unsigned short* __restrict__ w1l,
    const unsigned short* __restrict__ w2h, const unsigned short* __restrict__ w2l,
    const unsigned short* __restrict__ w3h, const unsigned short* __restrict__ w3l,
    const float* __restrict__ b1, const float* __restrict__ b2,
    const float* __restrict__ b3,
    float* __restrict__ out)        // [16][1024][128]
{
  const int N = 2048;
  const float r2 = (float)(0.2 * 0.2);
  const int tid = threadIdx.x;
  const int w = tid >> 6, lane = tid & 63;
  __shared__ __align__(16) unsigned short smem[4 * 4608];  // 36,864 B
  unsigned short* bufA_hi = smem;
  unsigned short* bufA_lo = smem + 4608;
  unsigned short* bufB_hi = smem + 9216;
  unsigned short* bufB_lo = smem + 13824;
  __shared__ int nb[64];
  __shared__ int tot[4];

  const int bs = blockIdx.x;
  const int b = bs >> 10;
  const float cx = ctr[bs * 3 + 0], cy = ctr[bs * 3 + 1], cz = ctr[bs * 3 + 2];
  // ---- ball query: masks in registers (wave w owns groups w*8..w*8+7) ----
  nb[lane] = 0;
  unsigned long long mloc[8];
  {
#pragma clang fp contract(off)
#pragma unroll
    for (int it = 0; it < 8; ++it) {
      int i = (w * 8 + it) * 64 + lane;
      const float* p = pos + ((size_t)b * N + i) * 3;
      float dx = p[0] - cx, dy = p[1] - cy, dz = p[2] - cz;
      float t0 = dx * dx, t1 = dy * dy, t2 = dz * dz;
      float d2 = (t0 + t1) + t2;
      mloc[it] = __ballot(d2 <= r2);
    }
  }
  {
    int mytot = 0;
#pragma unroll
    for (int it = 0; it < 8; ++it) mytot += (int)__popcll(mloc[it]);
    if (lane == 0) tot[w] = mytot;
  }
  __syncthreads();
  const int t0s = tot[0], t1s = tot[1], t2s = tot[2], t3s = tot[3];
  {
    int cnt = (w > 0 ? t0s : 0) + (w > 1 ? t1s : 0) + (w > 2 ? t2s : 0);
#pragma unroll
    for (int it = 0; it < 8; ++it) {
      unsigned long long m = mloc[it];
      bool inr = (m >> lane) & 1;
      int posn = cnt + (int)__popcll(m & ((1ull << lane) - 1ull));
      if (inr && posn < 64) nb[posn] = (w * 8 + it) * 64 + lane;
      cnt += (int)__popcll(m);
    }
  }
  const int total = t0s + t1s + t2s + t3s;
  const int nvalid = total < 64 ? total : 64;
  __syncthreads();  // nb complete & visible
  // ---- feature staging split across waves: w0..w2 -> x feats, w3 -> rel+pad
  {
    int j = nb[lane];
    if (w < 3) {
      const float* xr = x + ((size_t)b * N + j) * 9 + w * 3;
      float f0 = xr[0], f1 = xr[1], f2 = xr[2];
      unsigned short h, l;
      split_bf(f0, h, l); bufA_hi[lane * 72 + w * 3 + 0] = h; bufA_lo[lane * 72 + w * 3 + 0] = l;
      split_bf(f1, h, l); bufA_hi[lane * 72 + w * 3 + 1] = h; bufA_lo[lane * 72 + w * 3 + 1] = l;
      split_bf(f2, h, l); bufA_hi[lane * 72 + w * 3 + 2] = h; bufA_lo[lane * 72 + w * 3 + 2] = l;
    } else {
      const float* pr = pos + ((size_t)b * N + j) * 3;
      float rr[3] = {pr[0] - cx, pr[1] - cy, pr[2] - cz};
#pragma unroll
      for (int c = 0; c < 3; ++c) {
        unsigned short h, l;
        split_bf(rr[c], h, l);
        bufA_hi[lane * 72 + 9 + c] = h;
        bufA_lo[lane * 72 + 9 + c] = l;
      }
#pragma unroll
      for (int k = 12; k < 32; ++k) {
        bufA_hi[lane * 72 + k] = 0;
        bufA_lo[lane * 72 + k] = 0;
      }
    }
  }
  __syncthreads();
  {  // L1: K=32(12), N=64; wave n-slice [w*16, w*16+16)
    f32x4 acc[4][1];
    mfma_allm<1, 1>(bufA_hi, bufA_lo, 72, w1h, w1l, 40, b1, w * 16, lane, acc);
    store_allm<1>(acc, w * 16, bufB_hi, bufB_lo, 72, lane);
  }
  __syncthreads();
  {  // L2: K=64, N=64; reads B, writes A
    f32x4 acc[4][1];
    mfma_allm<2, 1>(bufB_hi, bufB_lo, 72, w2h, w2l, 72, b2, w * 16, lane, acc);
    store_allm<1>(acc, w * 16, bufA_hi, bufA_lo, 72, lane);
  }
  __syncthreads();
  {  // L3: K=64, N=128; wave n-slice [w*32, w*32+32) + pool
    f32x4 acc[4][2];
    mfma_allm<2, 2>(bufA_hi, bufA_lo, 72, w3h, w3l, 72, b3, w * 32, lane, acc);
    outpool_allm<2>(acc, w * 32, out + (size_t)bs * 128, nvalid, lane);
  }
}

// ---------------------------------------------------------------------------
// SA2 (MFMA, wave=n-slice): register-mask ball query + MLP + maxpool.
// ---------------------------------------------------------------------------
__global__ __launch_bounds__(256, 2) void sa2_kernel(
    const float* __restrict__ x1,   // [16][1024][128]
    const float* __restrict__ pos1, // [16][1024][3]
    const float* __restrict__ ctr,  // [16][256][3]
    const unsigned short* __restrict__ w1h, const unsigned short* __restrict__ w1l,
    const unsigned short* __restrict__ w2h, const unsigned short* __restrict__ w2l,
    const unsigned short* __restrict__ w3h, const unsigned short* __restrict__ w3l,
    const float* __restrict__ b1, const float* __restrict__ b2,
    const float* __restrict__ b3,
    float* __restrict__ out)        // [16][256][256]
{
  const int N = 1024;
  const float r2 = (float)(0.4 * 0.4);
  const int bs = blockIdx.x;
  const int b = bs >> 8;
  const int tid = threadIdx.x;
  const int w = tid >> 6, lane = tid & 63;
  const float cx = ctr[bs * 3 + 0], cy = ctr[bs * 3 + 1], cz = ctr[bs * 3 + 2];
  __shared__ __align__(16) unsigned short bufA_hi[64 * 168], bufA_lo[64 * 168];
  __shared__ __align__(16) unsigned short bufB_hi[64 * 136], bufB_lo[64 * 136];
  __shared__ int nb[64];
  __shared__ int tot[4];
  nb[lane] = 0;
  unsigned long long mloc[4];
  {
#pragma clang fp contract(off)
#pragma unroll
    for (int it = 0; it < 4; ++it) {
      int i = (w * 4 + it) * 64 + lane;
      const float* p = pos1 + ((size_t)b * N + i) * 3;
      float dx = p[0] - cx, dy = p[1] - cy, dz = p[2] - cz;
      float t0 = dx * dx, t1 = dy * dy, t2 = dz * dz;
      float d2 = (t0 + t1) + t2;
      mloc[it] = __ballot(d2 <= r2);
    }
  }
  {
    int mytot = 0;
#pragma unroll
    for (int it = 0; it < 4; ++it) mytot += (int)__popcll(mloc[it]);
    if (lane == 0) tot[w] = mytot;
  }
  __syncthreads();
  const int t0s = tot[0], t1s = tot[1], t2s = tot[2], t3s = tot[3];
  {
    int cnt = (w > 0 ? t0s : 0) + (w > 1 ? t1s : 0) + (w > 2 ? t2s : 0);
#pragma unroll
    for (int it = 0; it < 4; ++it) {
      unsigned long long m = mloc[it];
      bool inr = (m >> lane) & 1;
      int posn = cnt + (int)__popcll(m & ((1ull << lane) - 1ull));
      if (inr && posn < 64) nb[posn] = (w * 4 + it) * 64 + lane;
      cnt += (int)__popcll(m);
    }
  }
  const int total = t0s + t1s + t2s + t3s;
  const int nvalid = total < 64 ? total : 64;
  __syncthreads();  // nb complete & visible
  {  // stage features: quarter w loads k in [32w, 32w+32); w0 also rel+pad
    int j = nb[lane];
    const float* xr = x1 + ((size_t)b * N + j) * 128 + 32 * w;
#pragma unroll
    for (int g = 0; g < 8; ++g) {
      float4 v = *(const float4*)(xr + 4 * g);
      float vv[4] = {v.x, v.y, v.z, v.w};
#pragma unroll
      for (int e = 0; e < 4; ++e) {
        unsigned short h, l;
        split_bf(vv[e], h, l);
        int k = 32 * w + 4 * g + e;
        bufA_hi[lane * 168 + k] = h;
        bufA_lo[lane * 168 + k] = l;
      }
    }
    if (w == 0) {
      const float* pr = pos1 + ((size_t)b * N + j) * 3;
      float rr[3] = {pr[0] - cx, pr[1] - cy, pr[2] - cz};
#pragma unroll
      for (int c = 0; c < 3; ++c) {
        unsigned short h, l;
        split_bf(rr[c], h, l);
        bufA_hi[lane * 168 + 128 + c] = h;
        bufA_lo[lane * 168 + 128 + c] = l;
      }
#pragma unroll
      for (int k = 131; k < 160; ++k) {
        bufA_hi[lane * 168 + k] = 0;
        bufA_lo[lane * 168 + k] = 0;
      }
    }
  }
  __syncthreads();
  {  // L1: K=160(131), N=128; n-slice [w*32, w*32+32)
    f32x4 acc[4][2];
    mfma_allm<5, 2>(bufA_hi, bufA_lo, 168, w1h, w1l, 168, b1, w * 32, lane, acc);
    store_allm<2>(acc, w * 32, bufB_hi, bufB_lo, 136, lane);
  }
  __syncthreads();
  {  // L2: K=128, N=128; reads B, writes A
    f32x4 acc[4][2];
    mfma_allm<4, 2>(bufB_hi, bufB_lo, 136, w2h, w2l, 136, b2, w * 32, lane, acc);
    store_allm<2>(acc, w * 32, bufA_hi, bufA_lo, 168, lane);
  }
  __syncthreads();
  {  // L3: K=128, N=256; n-slice [w*64, w*64+64) + pool
    f32x4 acc[4][4];
    mfma_allm<4, 4>(bufA_hi, bufA_lo, 168, w3h, w3l, 136, b3, w * 64, lane, acc);
    outpool_allm<4>(acc, w * 64, out + (size_t)bs * 256, nvalid, lane);
  }
}

// ---------------------------------------------------------------------------
// Global SA (MFMA): MLP 259->256->512->1024, 16 points/block, wave=n-quarter.
// ---------------------------------------------------------------------------
__global__ __launch_bounds__(256, 2) void gsa_kernel(
    const float* __restrict__ x2,  // [16][256][256]
    const float* __restrict__ p2,  // [16][256][3]
    const unsigned short* __restrict__ g1h, const unsigned short* __restrict__ g1l,
    const unsigned short* __restrict__ g2h, const unsigned short* __restrict__ g2l,
    const unsigned short* __restrict__ g3h, const unsigned short* __restrict__ g3l,
    const float* __restrict__ b1, const float* __restrict__ b2,
    const float* __restrict__ b3,
    float* __restrict__ part)      // [16][16][1024]
{
  const int blk = blockIdx.x;  // 256
  const int bt = blk >> 4, gidx = blk & 15;
  const int tid = threadIdx.x;
  const int w = tid >> 6, lane = tid & 63;
  const int p0 = gidx * 16;
  __shared__ __align__(16) unsigned short inH[16 * 296], inL[16 * 296];
  __shared__ __align__(16) unsigned short h1H[16 * 264], h1L[16 * 264];
  __shared__ __align__(16) unsigned short h2H[16 * 520], h2L[16 * 520];
  {  // stage 16 points x 256 feats + 3 pos + zero pad to 288
    int p = tid >> 4, seg = tid & 15;
    const float* xr = x2 + ((size_t)(bt * 256 + p0 + p)) * 256 + seg * 16;
#pragma unroll
    for (int g = 0; g < 4; ++g) {
      float4 v = *(const float4*)(xr + 4 * g);
      float vv[4] = {v.x, v.y, v.z, v.w};
#pragma unroll
      for (int e = 0; e < 4; ++e) {
        unsigned short h, l;
        split_bf(vv[e], h, l);
        int k = seg * 16 + 4 * g + e;
        inH[p * 296 + k] = h;
        inL[p * 296 + k] = l;
      }
    }
    if (tid < 16) {
      const float* pr = p2 + (bt * 256 + p0 + tid) * 3;
#pragma unroll
      for (int c = 0; c < 3; ++c) {
        unsigned short h, l;
        split_bf(pr[c], h, l);
        inH[tid * 296 + 256 + c] = h;
        inL[tid * 296 + 256 + c] = l;
      }
      for (int k = 259; k < 288; ++k) {
        inH[tid * 296 + k] = 0;
        inL[tid * 296 + k] = 0;
      }
    }
  }
  __syncthreads();
  {  // L1: K=288(259), N=256
    f32x4 acc[4];
    mfma_1m<9, 4>(inH, inL, 296, g1h, g1l, 296, b1, w * 64, lane, acc);
    store_1m<4>(acc, w * 64, h1H, h1L, 264, lane);
  }
  __syncthreads();
  {  // L2: K=256, N=512
    f32x4 acc[8];
    mfma_1m<8, 8>(h1H, h1L, 264, g2h, g2l, 264, b2, w * 128, lane, acc);
    store_1m<8>(acc, w * 128, h2H, h2L, 520, lane);
  }
  __syncthreads();
  {  // L3: K=512, N=1024 + max over 16 points
    f32x4 acc[16];
    mfma_1m<16, 16>(h2H, h2L, 520, g3h, g3l, 520, b3, w * 256, lane, acc);
    const int col = lane & 15;
    float* op = part + ((size_t)(bt * 16 + gidx)) * 1024 + w * 256;
#pragma unroll
    for (int t = 0; t < 16; ++t) {
      float m = -DEVINF;
#pragma unroll
      for (int r = 0; r < 4; ++r) m = fmaxf(m, fmaxf(acc[t][r], 0.f));
      m = fmaxf(m, __shfl_xor(m, 16, 64));
      m = fmaxf(m, __shfl_xor(m, 32, 64));
      if ((lane >> 4) == 0) op[t * 16 + col] = m;
    }
  }
}

// ---------------------------------------------------------------------------
// head1: gmax + l1 + l2 + l3. One block per B-row (16 blocks).
// ---------------------------------------------------------------------------
__global__ __launch_bounds__(256) void head1_kernel(
    const float* __restrict__ part,  // [16][16][1024]
    const float* __restrict__ l1w, const float* __restrict__ l1b,
    const float* __restrict__ l2w, const float* __restrict__ l2b,
    const float* __restrict__ l3w, const float* __restrict__ l3b,
    float* __restrict__ hC)          // [16][256]
{
  const int m = blockIdx.x;
  const int tid = threadIdx.x;
  __shared__ float gA[1024];
  __shared__ float hX[512];
  __shared__ float hY[256];
#pragma unroll
  for (int j = 0; j < 4; ++j) {
    int c = j * 256 + tid;
    float mx = -DEVINF;
#pragma unroll
    for (int t = 0; t < 16; ++t)
      mx = fmaxf(mx, part[((size_t)(m * 16 + t)) * 1024 + c]);
    gA[c] = mx;
  }
  __syncthreads();
  {  // l1: 1024 -> 512, relu
    float a0 = l1b[tid], a1 = l1b[tid + 256];
#pragma unroll 4
    for (int k = 0; k < 1024; ++k) {
      float v = gA[k];
      a0 = fmaf(v, l1w[(size_t)k * 512 + tid], a0);
      a1 = fmaf(v, l1w[(size_t)k * 512 + tid + 256], a1);
    }
    hX[tid] = fmaxf(a0, 0.f);
    hX[tid + 256] = fmaxf(a1, 0.f);
  }
  __syncthreads();
  {  // l2: 512 -> 256, relu
    float a = l2b[tid];
#pragma unroll 4
    for (int k = 0; k < 512; ++k) a = fmaf(hX[k], l2w[(size_t)k * 256 + tid], a);
    hY[tid] = fmaxf(a, 0.f);
  }
  __syncthreads();
  {  // l3: 256 -> 256, no relu
    float a = l3b[tid];
#pragma unroll 4
    for (int k = 0; k < 256; ++k) a = fmaf(hY[k], l3w[(size_t)k * 256 + tid], a);
    hC[(size_t)m * 256 + tid] = a;
  }
}

// ---------------------------------------------------------------------------
// head2: fusion MLP (fw1,fw2,fw3) + l4 + l5. One block per fused row (4).
// ---------------------------------------------------------------------------
__global__ __launch_bounds__(256) void head2_kernel(
    const float* __restrict__ hC,  // [4][1024]
    const float* __restrict__ fw1, const float* __restrict__ fb1,
    const float* __restrict__ fw2, const float* __restrict__ fb2,
    const float* __restrict__ fw3, const float* __restrict__ fb3,
    const float* __restrict__ l4w, const float* __restrict__ l4b,
    const float* __restrict__ l5w, const float* __restrict__ l5b,
    float* __restrict__ out)       // [4][128]
{
  const int m = blockIdx.x;
  const int tid = threadIdx.x;
  __shared__ float A[1024];
  __shared__ float Bf[512];
#pragma unroll
  for (int j = 0; j < 4; ++j) A[j * 256 + tid] = hC[(size_t)m * 1024 + j * 256 + tid];
  __syncthreads();
  {  // fw1: 1024 -> 512 relu, A -> Bf
    float a0 = fb1[tid], a1 = fb1[tid + 256];
#pragma unroll 4
    for (int k = 0; k < 1024; ++k) {
      float v = A[k];
      a0 = fmaf(v, fw1[(size_t)k * 512 + tid], a0);
      a1 = fmaf(v, fw1[(size_t)k * 512 + tid + 256], a1);
    }
    Bf[tid] = fmaxf(a0, 0.f);
    Bf[tid + 256] = fmaxf(a1, 0.f);
  }
  __syncthreads();
  {  // fw2: 512 -> 512 relu, Bf -> A
    float a0 = fb2[tid], a1 = fb2[tid + 256];
#pragma unroll 4
    for (int k = 0; k < 512; ++k) {
      float v = Bf[k];
      a0 = fmaf(v, fw2[(size_t)k * 512 + tid], a0);
      a1 = fmaf(v, fw2[(size_t)k * 512 + tid + 256], a1);
    }
    __syncthreads();
    A[tid] = fmaxf(a0, 0.f);
    A[tid + 256] = fmaxf(a1, 0.f);
  }
  __syncthreads();
  {  // fw3: 512 -> 256 relu, A -> Bf
    float a = fb3[tid];
#pragma unroll 4
    for (int k = 0; k < 512; ++k) a = fmaf(A[k], fw3[(size_t)k * 256 + tid], a);
    __syncthreads();
    Bf[tid] = fmaxf(a, 0.f);
  }
  __syncthreads();
  {  // l4: 256 -> 128 relu, Bf -> A
    if (tid < 128) {
      float a = l4b[tid];
#pragma unroll 4
      for (int k = 0; k < 256; ++k) a = fmaf(Bf[k], l4w[(size_t)k * 128 + tid], a);
      A[tid] = fmaxf(a, 0.f);
    }
  }
  __syncthreads();
  {  // l5: 128 -> 128, A -> out
    if (tid < 128) {
      float a = l5b[tid];
#pragma unroll 4
      for (int k = 0; k < 128; ++k) a = fmaf(A[k], l5w[(size_t)k * 128 + tid], a);
      out[(size_t)m * 128 + tid] = a;
    }
  }
}

// ---------------------------------------------------------------------------
extern "C" void kernel_launch(void* const* d_in, const int* in_sizes, int n_in,
                              void* d_out, int out_size, void* d_ws, size_t ws_size,
                              hipStream_t stream) {
  (void)in_sizes; (void)n_in; (void)out_size; (void)ws_size;
  const float* x    = (const float*)d_in[0];
  const float* pos  = (const float*)d_in[1];
  const float* s1w1 = (const float*)d_in[2];  const float* s1b1 = (const float*)d_in[3];
  const float* s1w2 = (const float*)d_in[4];  const float* s1b2 = (const float*)d_in[5];
  const float* s1w3 = (const float*)d_in[6];  const float* s1b3 = (const float*)d_in[7];
  const float* s2w1 = (const float*)d_in[8];  const float* s2b1 = (const float*)d_in[9];
  const float* s2w2 = (const float*)d_in[10]; const float* s2b2 = (const float*)d_in[11];
  const float* s2w3 = (const float*)d_in[12]; const float* s2b3 = (const float*)d_in[13];
  const float* s3w1 = (const float*)d_in[14]; const float* s3b1 = (const float*)d_in[15];
  const float* s3w2 = (const float*)d_in[16]; const float* s3b2 = (const float*)d_in[17];
  const float* s3w3 = (const float*)d_in[18]; const float* s3b3 = (const float*)d_in[19];
  const float* fw1  = (const float*)d_in[20]; const float* fb1  = (const float*)d_in[21];
  const float* fw2  = (const float*)d_in[22]; const float* fb2  = (const float*)d_in[23];
  const float* fw3  = (const float*)d_in[24]; const float* fb3  = (const float*)d_in[25];
  const float* l1w  = (const float*)d_in[26]; const float* l1b  = (const float*)d_in[27];
  const float* l2w  = (const float*)d_in[28]; const float* l2b  = (const float*)d_in[29];
  const float* l3w  = (const float*)d_in[30]; const float* l3b  = (const float*)d_in[31];
  const float* l4w  = (const float*)d_in[32]; const float* l4b  = (const float*)d_in[33];
  const float* l5w  = (const float*)d_in[34]; const float* l5b  = (const float*)d_in[35];
  float* out = (float*)d_out;

  float* ws = (float*)d_ws;
  float* p1   = ws;                  // 16*1024*3
  float* x1   = p1 + 49152;          // 16*1024*128
  float* p2   = x1 + 2097152;        // 16*256*3
  float* x2   = p2 + 12288;          // 16*256*256
  float* part = x2 + 1048576;        // 16*16*1024
  float* hC   = part + 262144;       // 16*256
  // bf16 hi/lo transposed weight planes (u16)
  unsigned short* wp = (unsigned short*)(hC + 4096);
  unsigned short* s1w1h = wp;              unsigned short* s1w1l = s1w1h + 2560;    // [64][40]
  unsigned short* s1w2h = s1w1l + 2560;    unsigned short* s1w2l = s1w2h + 4608;    // [64][72]
  unsigned short* s1w3h = s1w2l + 4608;    unsigned short* s1w3l = s1w3h + 9216;    // [128][72]
  unsigned short* s2w1h = s1w3l + 9216;    unsigned short* s2w1l = s2w1h + 21504;   // [128][168]
  unsigned short* s2w2h = s2w1l + 21504;   unsigned short* s2w2l = s2w2h + 17408;   // [128][136]
  unsigned short* s2w3h = s2w2l + 17408;   unsigned short* s2w3l = s2w3h + 34816;   // [256][136]
  unsigned short* g1h   = s2w3l + 34816;   unsigned short* g1l   = g1h + 75776;     // [256][296]
  unsigned short* g2h   = g1l + 75776;     unsigned short* g2l   = g2h + 135168;    // [512][264]
  unsigned short* g3h   = g2l + 135168;    unsigned short* g3l   = g3h + 532480;    // [1024][520]

  PrepJobs jb;
  const float* srcs[9] = {s1w1, s1w2, s1w3, s2w1, s2w2, s2w3, s3w1, s3w2, s3w3};
  unsigned short* his[9] = {s1w1h, s1w2h, s1w3h, s2w1h, s2w2h, s2w3h, g1h, g2h, g3h};
  unsigned short* los[9] = {s1w1l, s1w2l, s1w3l, s2w1l, s2w2l, s2w3l, g1l, g2l, g3l};
  int Ks[9]  = {12, 64, 64, 131, 128, 128, 259, 256, 512};
  int Ns[9]  = {64, 64, 128, 128, 128, 256, 256, 512, 1024};
  int rls[9] = {40, 72, 72, 168, 136, 136, 296, 264, 520};
  int acc_blk = 0;
  for (int j = 0; j < 9; ++j) {
    jb.src[j] = srcs[j]; jb.hi[j] = his[j]; jb.lo[j] = los[j];
    jb.K[j] = Ks[j]; jb.N[j] = Ns[j]; jb.rl[j] = rls[j];
    jb.blk0[j] = acc_blk;
    acc_blk += (Ns[j] * rls[j] + 255) / 256;   // 256-thread granularity
  }
  jb.blk0[9] = acc_blk;

  fps_prep_kernel<<<16 + acc_blk, 256, 0, stream>>>(pos, p1, p2, jb);
  sa1_kernel<<<16 * 1024, 256, 0, stream>>>(x, pos, p1, s1w1h, s1w1l,
                                            s1w2h, s1w2l, s1w3h, s1w3l,
                                            s1b1, s1b2, s1b3, x1);
  sa2_kernel<<<16 * 256, 256, 0, stream>>>(x1, p1, p2, s2w1h, s2w1l, s2w2h,
                                           s2w2l, s2w3h, s2w3l, s2b1, s2b2,
                                           s2b3, x2);
  gsa_kernel<<<256, 256, 0, stream>>>(x2, p2, g1h, g1l, g2h, g2l, g3h, g3l,
                                      s3b1, s3b2, s3b3, part);
  head1_kernel<<<16, 256, 0, stream>>>(part, l1w, l1b, l2w, l2b, l3w, l3b, hC);
  head2_kernel<<<4, 256, 0, stream>>>(hC, fw1, fb1, fw2, fb2, fw3, fb3, l4w,
                                      l4b, l5w, l5b, out);
}

// Round 11
// 1498.328 us; speedup vs baseline: 1.0582x; 1.0582x over previous
//
#include <hip/hip_runtime.h>
#include <cstddef>

#define DEVINF __builtin_inff()

typedef __attribute__((ext_vector_type(8))) short bf16x8;
typedef __attribute__((ext_vector_type(4))) float f32x4;
typedef __attribute__((ext_vector_type(2))) float f32x2;

__device__ __forceinline__ unsigned short f2bf(float x) {
  unsigned u = __float_as_uint(x);
  return (unsigned short)((u + 0x7fff + ((u >> 16) & 1)) >> 16);
}
__device__ __forceinline__ float bf2f(unsigned short h) {
  return __uint_as_float(((unsigned)h) << 16);
}
__device__ __forceinline__ void split_bf(float x, unsigned short& hi, unsigned short& lo) {
  hi = f2bf(x);
  lo = f2bf(x - bf2f(hi));
}

// ---------------------------------------------------------------------------
// FPS cooperative step: each wave updates its own point range, reduces to a
// per-wave winner key via DPP (lane 63 holds it). Key = (val_bits<<32)|~idx:
// u64 max == (max val, lowest idx) == numpy first-max. Keys are unique (idx
// embedded), so cross-wave fold by key picks a unique winner.
// ---------------------------------------------------------------------------
#define FPS_RED_LEVEL(CTRL)                                                      \
  {                                                                              \
    int th = __builtin_amdgcn_update_dpp((int)hi, (int)hi, CTRL, 0xf, 0xf, false); \
    int tl = __builtin_amdgcn_update_dpp((int)lo, (int)lo, CTRL, 0xf, 0xf, false); \
    bool take = ((unsigned)th > hi) || (((unsigned)th == hi) && ((unsigned)tl > lo)); \
    hi = take ? (unsigned)th : hi;                                               \
    lo = take ? (unsigned)tl : lo;                                               \
  }

template <int PPLH, int NCH>
__device__ __forceinline__ unsigned long long fps_wave_step(
    f32x2* qx, f32x2* qy, f32x2* qz, f32x2* d, float lx, float ly, float lz,
    int lane, int ibase) {
#pragma clang fp contract(off)
  const int CH = PPLH / NCH;
  float bv[NCH];
  int bi[NCH];
#pragma unroll
  for (int c = 0; c < NCH; ++c) { bv[c] = -DEVINF; bi[c] = 0x7fffffff; }
  f32x2 lxv = {lx, lx}, lyv = {ly, ly}, lzv = {lz, lz};
#pragma unroll
  for (int h = 0; h < PPLH; ++h) {
    const int c = h / CH;
    f32x2 dx = qx[h] - lxv, dy = qy[h] - lyv, dz = qz[h] - lzv;
    f32x2 t0 = dx * dx, t1 = dy * dy, t2 = dz * dz;
    f32x2 d2 = (t0 + t1) + t2;
    f32x2 dn;
    dn.x = fminf(d[h].x, d2.x);
    dn.y = fminf(d[h].y, d2.y);
    d[h] = dn;
    int i0 = ibase + (2 * h) * 64 + lane;
    if (dn.x > bv[c]) { bv[c] = dn.x; bi[c] = i0; }
    if (dn.y > bv[c]) { bv[c] = dn.y; bi[c] = i0 + 64; }
  }
  unsigned hi, lo;
  if (NCH == 4) {
    unsigned h0 = __float_as_uint(bv[0]), l0 = ~(unsigned)bi[0];
    unsigned h1 = __float_as_uint(bv[1]), l1 = ~(unsigned)bi[1];
    unsigned h2 = __float_as_uint(bv[2]), l2 = ~(unsigned)bi[2];
    unsigned h3 = __float_as_uint(bv[3]), l3 = ~(unsigned)bi[3];
    bool t01 = (h1 > h0) || ((h1 == h0) && (l1 > l0));
    unsigned ha = t01 ? h1 : h0, la = t01 ? l1 : l0;
    bool t23 = (h3 > h2) || ((h3 == h2) && (l3 > l2));
    unsigned hb = t23 ? h3 : h2, lb = t23 ? l3 : l2;
    bool tab = (hb > ha) || ((hb == ha) && (lb > la));
    hi = tab ? hb : ha;
    lo = tab ? lb : la;
  } else {
    const int c1 = (NCH > 1) ? 1 : 0;
    unsigned h0 = __float_as_uint(bv[0]), l0 = ~(unsigned)bi[0];
    unsigned h1 = __float_as_uint(bv[c1]), l1 = ~(unsigned)bi[c1];
    bool t01 = (h1 > h0) || ((h1 == h0) && (l1 > l0));
    hi = t01 ? h1 : h0;
    lo = t01 ? l1 : l0;
  }
  FPS_RED_LEVEL(0x111)  // row_shr:1
  FPS_RED_LEVEL(0x112)  // row_shr:2
  FPS_RED_LEVEL(0x114)  // row_shr:4
  FPS_RED_LEVEL(0x118)  // row_shr:8
  FPS_RED_LEVEL(0x142)  // row_bcast:15
  FPS_RED_LEVEL(0x143)  // row_bcast:31
  return (((unsigned long long)hi) << 32) | lo;  // valid on lane 63
}

// ---------------------------------------------------------------------------
// prep jobs table (weight transposes fused into fps1 launch, 256-granular).
// ---------------------------------------------------------------------------
struct PrepJobs {
  const float* src[9];
  unsigned short* hi[9];
  unsigned short* lo[9];
  int K[9], N[9], rl[9];
  int blk0[10];
};

// ---------------------------------------------------------------------------
// fps1 (blocks 0..15): 2048 -> 1024 centers. Coord-carrying key exchange:
// lane 63 looks up its wave-winner's float4 BEFORE the barrier (latency
// hidden) and publishes (key, coords); after the barrier all lanes fold the
// 4 keys and select coords directly — no serial p4[last] read per step.
// blocks 16..: weight prep.
// ---------------------------------------------------------------------------
__global__ __launch_bounds__(256, 1) void fps1_prep_kernel(
    const float* __restrict__ pos, float* __restrict__ p1, PrepJobs jb) {
#pragma clang fp contract(off)
  const int tid = threadIdx.x;
  if (blockIdx.x >= 16) {
    int blk = blockIdx.x - 16;
    int j = 0;
#pragma unroll
    for (int t = 1; t < 9; ++t)
      if (blk >= jb.blk0[t]) j = t;
    int idx = (blk - jb.blk0[j]) * 256 + tid;
    int rl = jb.rl[j], N = jb.N[j], K = jb.K[j];
    if (idx >= N * rl) return;
    int n = idx / rl, k = idx - n * rl;
    float v = (k < K) ? jb.src[j][(size_t)k * N + n] : 0.f;
    unsigned short h, l;
    split_bf(v, h, l);
    jb.hi[j][idx] = h;
    jb.lo[j][idx] = l;
    return;
  }
  const int b = blockIdx.x;
  const int w = tid >> 6, lane = tid & 63;
  __shared__ __align__(16) float4 p4[2048];
  __shared__ __align__(16) float4 carr[1024];
  __shared__ unsigned long long kvk[2][4];
  __shared__ __align__(16) float4 kvc[2][4];
  f32x2 qx[4], qy[4], qz[4], d[4];
  const int ibase = w * 512;
#pragma unroll
  for (int h = 0; h < 4; ++h) {
    int i0 = ibase + (2 * h) * 64 + lane, i1 = i0 + 64;
    const float* a = pos + ((size_t)b * 2048 + i0) * 3;
    const float* c = pos + ((size_t)b * 2048 + i1) * 3;
    float x0 = a[0], y0 = a[1], z0 = a[2];
    float x1 = c[0], y1 = c[1], z1 = c[2];
    qx[h].x = x0; qx[h].y = x1;
    qy[h].x = y0; qy[h].y = y1;
    qz[h].x = z0; qz[h].y = z1;
    d[h].x = DEVINF; d[h].y = DEVINF;
    p4[i0] = float4{x0, y0, z0, 0.f};
    p4[i1] = float4{x1, y1, z1, 0.f};
  }
  __syncthreads();
  float4 c4 = p4[0];
  for (int s = 0; s < 1024; ++s) {
    if (tid == 0) carr[s] = c4;
    unsigned long long k =
        fps_wave_step<4, 4>(qx, qy, qz, d, c4.x, c4.y, c4.z, lane, ibase);
    if (lane == 63) {
      kvk[s & 1][w] = k;
      kvc[s & 1][w] = p4[(int)~(unsigned)k];
    }
    __syncthreads();
    unsigned long long k0 = kvk[s & 1][0], k1 = kvk[s & 1][1];
    unsigned long long k2 = kvk[s & 1][2], k3 = kvk[s & 1][3];
    float4 c0 = kvc[s & 1][0], c1 = kvc[s & 1][1];
    float4 c2 = kvc[s & 1][2], c3 = kvc[s & 1][3];
    bool ta = k1 > k0;
    unsigned long long ka = ta ? k1 : k0;
    float4 ca = ta ? c1 : c0;
    bool tb = k3 > k2;
    unsigned long long kb = tb ? k3 : k2;
    float4 cb = tb ? c3 : c2;
    c4 = (kb > ka) ? cb : ca;
  }
  for (int i = tid; i < 1024; i += 256) {
    float4 c = carr[i];
    p1[((size_t)b * 1024 + i) * 3 + 0] = c.x;
    p1[((size_t)b * 1024 + i) * 3 + 1] = c.y;
    p1[((size_t)b * 1024 + i) * 3 + 2] = c.z;
  }
}

// ---------------------------------------------------------------------------
// MFMA building blocks (B fragments loaded once per 12 MFMAs).
// ---------------------------------------------------------------------------
template <int KS, int T>
__device__ __forceinline__ void mfma_allm(
    const unsigned short* __restrict__ inHi, const unsigned short* __restrict__ inLo,
    int sIn, const unsigned short* __restrict__ wHi,
    const unsigned short* __restrict__ wLo, int rl, const float* __restrict__ bias,
    int n0, int lane, f32x4 acc[4][T]) {
  const int col = lane & 15, quad = lane >> 4;
#pragma unroll
  for (int t = 0; t < T; ++t) {
    float bv = bias[n0 + t * 16 + col];
#pragma unroll
    for (int mt = 0; mt < 4; ++mt) {
      acc[mt][t].x = bv; acc[mt][t].y = bv; acc[mt][t].z = bv; acc[mt][t].w = bv;
    }
  }
#pragma unroll 1
  for (int ks = 0; ks < KS; ++ks) {
    bf16x8 ah[4], al[4];
#pragma unroll
    for (int mt = 0; mt < 4; ++mt) {
      int aoff = (mt * 16 + col) * sIn + ks * 32 + quad * 8;
      ah[mt] = *(const bf16x8*)(inHi + aoff);
      al[mt] = *(const bf16x8*)(inLo + aoff);
    }
#pragma unroll
    for (int t = 0; t < T; ++t) {
      size_t boff = (size_t)(n0 + t * 16 + col) * rl + ks * 32 + quad * 8;
      bf16x8 bh = *(const bf16x8*)(wHi + boff);
      bf16x8 bl = *(const bf16x8*)(wLo + boff);
#pragma unroll
      for (int mt = 0; mt < 4; ++mt) {
        acc[mt][t] = __builtin_amdgcn_mfma_f32_16x16x32_bf16(ah[mt], bh, acc[mt][t], 0, 0, 0);
        acc[mt][t] = __builtin_amdgcn_mfma_f32_16x16x32_bf16(ah[mt], bl, acc[mt][t], 0, 0, 0);
        acc[mt][t] = __builtin_amdgcn_mfma_f32_16x16x32_bf16(al[mt], bh, acc[mt][t], 0, 0, 0);
      }
    }
  }
}

template <int T>
__device__ __forceinline__ void store_allm(const f32x4 acc[4][T], int n0,
                                           unsigned short* outHi,
                                           unsigned short* outLo, int sOut,
                                           int lane) {
  const int col = lane & 15, quad = lane >> 4;
#pragma unroll
  for (int mt = 0; mt < 4; ++mt)
#pragma unroll
    for (int t = 0; t < T; ++t)
#pragma unroll
      for (int r = 0; r < 4; ++r) {
        int edge = mt * 16 + quad * 4 + r;
        float v = fmaxf(acc[mt][t][r], 0.f);
        unsigned short h, l;
        split_bf(v, h, l);
        outHi[edge * sOut + n0 + t * 16 + col] = h;
        outLo[edge * sOut + n0 + t * 16 + col] = l;
      }
}

template <int T>
__device__ __forceinline__ void outpool_allm(const f32x4 acc[4][T], int n0,
                                             float* __restrict__ outp, int nvalid,
                                             int lane) {
  const int col = lane & 15, quad = lane >> 4;
#pragma unroll
  for (int t = 0; t < T; ++t) {
    float m = -DEVINF;
#pragma unroll
    for (int mt = 0; mt < 4; ++mt)
#pragma unroll
      for (int r = 0; r < 4; ++r) {
        int edge = mt * 16 + quad * 4 + r;
        float v = fmaxf(acc[mt][t][r], 0.f);
        if (edge >= nvalid) v = -DEVINF;
        m = fmaxf(m, v);
      }
    m = fmaxf(m, __shfl_xor(m, 16, 64));
    m = fmaxf(m, __shfl_xor(m, 32, 64));
    if (quad == 0) outp[n0 + t * 16 + col] = m;
  }
}

// single-m-tile variants (gsa)
template <int KS, int T>
__device__ __forceinline__ void mfma_1m(
    const unsigned short* __restrict__ inHi, const unsigned short* __restrict__ inLo,
    int sIn, const unsigned short* __restrict__ wHi,
    const unsigned short* __restrict__ wLo, int rl, const float* __restrict__ bias,
    int n0, int lane, f32x4 acc[T]) {
  const int col = lane & 15, quad = lane >> 4;
#pragma unroll
  for (int t = 0; t < T; ++t) {
    float bv = bias[n0 + t * 16 + col];
    acc[t].x = bv; acc[t].y = bv; acc[t].z = bv; acc[t].w = bv;
  }
#pragma unroll 1
  for (int ks = 0; ks < KS; ++ks) {
    int aoff = col * sIn + ks * 32 + quad * 8;
    bf16x8 ah = *(const bf16x8*)(inHi + aoff);
    bf16x8 al = *(const bf16x8*)(inLo + aoff);
#pragma unroll
    for (int t = 0; t < T; ++t) {
      size_t boff = (size_t)(n0 + t * 16 + col) * rl + ks * 32 + quad * 8;
      bf16x8 bh = *(const bf16x8*)(wHi + boff);
      bf16x8 bl = *(const bf16x8*)(wLo + boff);
      acc[t] = __builtin_amdgcn_mfma_f32_16x16x32_bf16(ah, bh, acc[t], 0, 0, 0);
      acc[t] = __builtin_amdgcn_mfma_f32_16x16x32_bf16(ah, bl, acc[t], 0, 0, 0);
      acc[t] = __builtin_amdgcn_mfma_f32_16x16x32_bf16(al, bh, acc[t], 0, 0, 0);
    }
  }
}

template <int T>
__device__ __forceinline__ void store_1m(const f32x4 acc[T], int n0,
                                         unsigned short* outHi,
                                         unsigned short* outLo, int sOut, int lane) {
  const int col = lane & 15, quad = lane >> 4;
#pragma unroll
  for (int t = 0; t < T; ++t)
#pragma unroll
    for (int r = 0; r < 4; ++r) {
      int p = quad * 4 + r;
      float v = fmaxf(acc[t][r], 0.f);
      unsigned short h, l;
      split_bf(v, h, l);
      outHi[p * sOut + n0 + t * 16 + col] = h;
      outLo[p * sOut + n0 + t * 16 + col] = l;
    }
}

// ---------------------------------------------------------------------------
// SA1 (MFMA, wave=n-slice) + EMBEDDED fps2 (blocks 0..15) — fps2 rides
// hidden under sa1's duration (measured round 9 vs 10). fps2 uses the same
// coord-carrying key exchange as fps1.
// ---------------------------------------------------------------------------
__global__ __launch_bounds__(256, 4) void sa1_kernel(
    const float* __restrict__ x,    // [16][2048][9]
    const float* __restrict__ pos,  // [16][2048][3]
    const float* __restrict__ ctr,  // p1: [16][1024][3]
    float* __restrict__ p2,         // [16][256][3] (fps2 output)
    const unsigned short* __restrict__ w1h, const unsigned short* __restrict__ w1l,
    const unsigned short* __restrict__ w2h, const unsigned short* __restrict__ w2l,
    const unsigned short* __restrict__ w3h, const unsigned short* __restrict__ w3l,
    const float* __restrict__ b1, const float* __restrict__ b2,
    const float* __restrict__ b3,
    float* __restrict__ out)        // [16][1024][128]
{
  const int N = 2048;
  const float r2 = (float)(0.2 * 0.2);
  const int tid = threadIdx.x;
  const int w = tid >> 6, lane = tid & 63;
  __shared__ __align__(16) unsigned short smem[4 * 4608];  // 36,864 B
  unsigned short* bufA_hi = smem;
  unsigned short* bufA_lo = smem + 4608;
  unsigned short* bufB_hi = smem + 9216;
  unsigned short* bufB_lo = smem + 13824;
  __shared__ int nb[64];
  __shared__ int tot[4];
  __shared__ unsigned long long kvk2[2][4];
  __shared__ __align__(16) float4 kvc2[2][4];

  if (blockIdx.x < 16) {
    // ------------- fps2: 1024 -> 256 centers, 4-wave cooperative -------------
    const int bb = blockIdx.x;
    float4* q4 = (float4*)smem;              // bytes 0..16383
    float4* carr = (float4*)(smem + 8192);   // bytes 16384..20479
    for (int i = tid; i < 1024; i += 256) {
      const float* pr = ctr + ((size_t)bb * 1024 + i) * 3;
      q4[i] = float4{pr[0], pr[1], pr[2], 0.f};
    }
    __syncthreads();
    f32x2 qx[2], qy[2], qz[2], d[2];
    const int ibase = w * 256;
#pragma unroll
    for (int h = 0; h < 2; ++h) {
      int i0 = ibase + (2 * h) * 64 + lane, i1 = i0 + 64;
      float4 a = q4[i0], c = q4[i1];
      qx[h].x = a.x; qx[h].y = c.x;
      qy[h].x = a.y; qy[h].y = c.y;
      qz[h].x = a.z; qz[h].y = c.z;
      d[h].x = DEVINF; d[h].y = DEVINF;
    }
    float4 c4 = q4[0];
    for (int s = 0; s < 256; ++s) {
      if (tid == 0) carr[s] = c4;
      unsigned long long k =
          fps_wave_step<2, 2>(qx, qy, qz, d, c4.x, c4.y, c4.z, lane, ibase);
      if (lane == 63) {
        kvk2[s & 1][w] = k;
        kvc2[s & 1][w] = q4[(int)~(unsigned)k];
      }
      __syncthreads();
      unsigned long long k0 = kvk2[s & 1][0], k1 = kvk2[s & 1][1];
      unsigned long long k2 = kvk2[s & 1][2], k3 = kvk2[s & 1][3];
      float4 c0 = kvc2[s & 1][0], c1 = kvc2[s & 1][1];
      float4 c2 = kvc2[s & 1][2], c3 = kvc2[s & 1][3];
      bool ta = k1 > k0;
      unsigned long long ka = ta ? k1 : k0;
      float4 ca = ta ? c1 : c0;
      bool tb = k3 > k2;
      unsigned long long kb = tb ? k3 : k2;
      float4 cb = tb ? c3 : c2;
      c4 = (kb > ka) ? cb : ca;
    }
    if (tid < 256) {
      float4 c = carr[tid];
      p2[((size_t)bb * 256 + tid) * 3 + 0] = c.x;
      p2[((size_t)bb * 256 + tid) * 3 + 1] = c.y;
      p2[((size_t)bb * 256 + tid) * 3 + 2] = c.z;
    }
    return;
  }

  const int bs = blockIdx.x - 16;
  const int b = bs >> 10;
  const float cx = ctr[bs * 3 + 0], cy = ctr[bs * 3 + 1], cz = ctr[bs * 3 + 2];
  // ---- ball query: masks in registers (wave w owns groups w*8..w*8+7) ----
  nb[lane] = 0;
  unsigned long long mloc[8];
  {
#pragma clang fp contract(off)
#pragma unroll
    for (int it = 0; it < 8; ++it) {
      int i = (w * 8 + it) * 64 + lane;
      const float* p = pos + ((size_t)b * N + i) * 3;
      float dx = p[0] - cx, dy = p[1] - cy, dz = p[2] - cz;
      float t0 = dx * dx, t1 = dy * dy, t2 = dz * dz;
      float d2 = (t0 + t1) + t2;
      mloc[it] = __ballot(d2 <= r2);
    }
  }
  {
    int mytot = 0;
#pragma unroll
    for (int it = 0; it < 8; ++it) mytot += (int)__popcll(mloc[it]);
    if (lane == 0) tot[w] = mytot;
  }
  __syncthreads();
  const int t0s = tot[0], t1s = tot[1], t2s = tot[2], t3s = tot[3];
  {
    int cnt = (w > 0 ? t0s : 0) + (w > 1 ? t1s : 0) + (w > 2 ? t2s : 0);
#pragma unroll
    for (int it = 0; it < 8; ++it) {
      unsigned long long m = mloc[it];
      bool inr = (m >> lane) & 1;
      int posn = cnt + (int)__popcll(m & ((1ull << lane) - 1ull));
      if (inr && posn < 64) nb[posn] = (w * 8 + it) * 64 + lane;
      cnt += (int)__popcll(m);
    }
  }
  const int total = t0s + t1s + t2s + t3s;
  const int nvalid = total < 64 ? total : 64;
  __syncthreads();  // nb complete & visible
  // ---- feature staging split across waves: w0..w2 -> x feats, w3 -> rel+pad
  {
    int j = nb[lane];
    if (w < 3) {
      const float* xr = x + ((size_t)b * N + j) * 9 + w * 3;
      float f0 = xr[0], f1 = xr[1], f2 = xr[2];
      unsigned short h, l;
      split_bf(f0, h, l); bufA_hi[lane * 72 + w * 3 + 0] = h; bufA_lo[lane * 72 + w * 3 + 0] = l;
      split_bf(f1, h, l); bufA_hi[lane * 72 + w * 3 + 1] = h; bufA_lo[lane * 72 + w * 3 + 1] = l;
      split_bf(f2, h, l); bufA_hi[lane * 72 + w * 3 + 2] = h; bufA_lo[lane * 72 + w * 3 + 2] = l;
    } else {
      const float* pr = pos + ((size_t)b * N + j) * 3;
      float rr[3] = {pr[0] - cx, pr[1] - cy, pr[2] - cz};
#pragma unroll
      for (int c = 0; c < 3; ++c) {
        unsigned short h, l;
        split_bf(rr[c], h, l);
        bufA_hi[lane * 72 + 9 + c] = h;
        bufA_lo[lane * 72 + 9 + c] = l;
      }
#pragma unroll
      for (int k = 12; k < 32; ++k) {
        bufA_hi[lane * 72 + k] = 0;
        bufA_lo[lane * 72 + k] = 0;
      }
    }
  }
  __syncthreads();
  {  // L1: K=32(12), N=64; wave n-slice [w*16, w*16+16)
    f32x4 acc[4][1];
    mfma_allm<1, 1>(bufA_hi, bufA_lo, 72, w1h, w1l, 40, b1, w * 16, lane, acc);
    store_allm<1>(acc, w * 16, bufB_hi, bufB_lo, 72, lane);
  }
  __syncthreads();
  {  // L2: K=64, N=64; reads B, writes A
    f32x4 acc[4][1];
    mfma_allm<2, 1>(bufB_hi, bufB_lo, 72, w2h, w2l, 72, b2, w * 16, lane, acc);
    store_allm<1>(acc, w * 16, bufA_hi, bufA_lo, 72, lane);
  }
  __syncthreads();
  {  // L3: K=64, N=128; wave n-slice [w*32, w*32+32) + pool
    f32x4 acc[4][2];
    mfma_allm<2, 2>(bufA_hi, bufA_lo, 72, w3h, w3l, 72, b3, w * 32, lane, acc);
    outpool_allm<2>(acc, w * 32, out + (size_t)bs * 128, nvalid, lane);
  }
}

// ---------------------------------------------------------------------------
// SA2 (MFMA, wave=n-slice): register-mask ball query + MLP + maxpool.
// ---------------------------------------------------------------------------
__global__ __launch_bounds__(256, 2) void sa2_kernel(
    const float* __restrict__ x1,   // [16][1024][128]
    const float* __restrict__ pos1, // [16][1024][3]
    const float* __restrict__ ctr,  // [16][256][3]
    const unsigned short* __restrict__ w1h, const unsigned short* __restrict__ w1l,
    const unsigned short* __restrict__ w2h, const unsigned short* __restrict__ w2l,
    const unsigned short* __restrict__ w3h, const unsigned short* __restrict__ w3l,
    const float* __restrict__ b1, const float* __restrict__ b2,
    const float* __restrict__ b3,
    float* __restrict__ out)        // [16][256][256]
{
  const int N = 1024;
  const float r2 = (float)(0.4 * 0.4);
  const int bs = blockIdx.x;
  const int b = bs >> 8;
  const int tid = threadIdx.x;
  const int w = tid >> 6, lane = tid & 63;
  const float cx = ctr[bs * 3 + 0], cy = ctr[bs * 3 + 1], cz = ctr[bs * 3 + 2];
  __shared__ __align__(16) unsigned short bufA_hi[64 * 168], bufA_lo[64 * 168];
  __shared__ __align__(16) unsigned short bufB_hi[64 * 136], bufB_lo[64 * 136];
  __shared__ int nb[64];
  __shared__ int tot[4];
  nb[lane] = 0;
  unsigned long long mloc[4];
  {
#pragma clang fp contract(off)
#pragma unroll
    for (int it = 0; it < 4; ++it) {
      int i = (w * 4 + it) * 64 + lane;
      const float* p = pos1 + ((size_t)b * N + i) * 3;
      float dx = p[0] - cx, dy = p[1] - cy, dz = p[2] - cz;
      float t0 = dx * dx, t1 = dy * dy, t2 = dz * dz;
      float d2 = (t0 + t1) + t2;
      mloc[it] = __ballot(d2 <= r2);
    }
  }
  {
    int mytot = 0;
#pragma unroll
    for (int it = 0; it < 4; ++it) mytot += (int)__popcll(mloc[it]);
    if (lane == 0) tot[w] = mytot;
  }
  __syncthreads();
  const int t0s = tot[0], t1s = tot[1], t2s = tot[2], t3s = tot[3];
  {
    int cnt = (w > 0 ? t0s : 0) + (w > 1 ? t1s : 0) + (w > 2 ? t2s : 0);
#pragma unroll
    for (int it = 0; it < 4; ++it) {
      unsigned long long m = mloc[it];
      bool inr = (m >> lane) & 1;
      int posn = cnt + (int)__popcll(m & ((1ull << lane) - 1ull));
      if (inr && posn < 64) nb[posn] = (w * 4 + it) * 64 + lane;
      cnt += (int)__popcll(m);
    }
  }
  const int total = t0s + t1s + t2s + t3s;
  const int nvalid = total < 64 ? total : 64;
  __syncthreads();  // nb complete & visible
  {  // stage features: quarter w loads k in [32w, 32w+32); w0 also rel+pad
    int j = nb[lane];
    const float* xr = x1 + ((size_t)b * N + j) * 128 + 32 * w;
#pragma unroll
    for (int g = 0; g < 8; ++g) {
      float4 v = *(const float4*)(xr + 4 * g);
      float vv[4] = {v.x, v.y, v.z, v.w};
#pragma unroll
      for (int e = 0; e < 4; ++e) {
        unsigned short h, l;
        split_bf(vv[e], h, l);
        int k = 32 * w + 4 * g + e;
        bufA_hi[lane * 168 + k] = h;
        bufA_lo[lane * 168 + k] = l;
      }
    }
    if (w == 0) {
      const float* pr = pos1 + ((size_t)b * N + j) * 3;
      float rr[3] = {pr[0] - cx, pr[1] - cy, pr[2] - cz};
#pragma unroll
      for (int c = 0; c < 3; ++c) {
        unsigned short h, l;
        split_bf(rr[c], h, l);
        bufA_hi[lane * 168 + 128 + c] = h;
        bufA_lo[lane * 168 + 128 + c] = l;
      }
#pragma unroll
      for (int k = 131; k < 160; ++k) {
        bufA_hi[lane * 168 + k] = 0;
        bufA_lo[lane * 168 + k] = 0;
      }
    }
  }
  __syncthreads();
  {  // L1: K=160(131), N=128; n-slice [w*32, w*32+32)
    f32x4 acc[4][2];
    mfma_allm<5, 2>(bufA_hi, bufA_lo, 168, w1h, w1l, 168, b1, w * 32, lane, acc);
    store_allm<2>(acc, w * 32, bufB_hi, bufB_lo, 136, lane);
  }
  __syncthreads();
  {  // L2: K=128, N=128; reads B, writes A
    f32x4 acc[4][2];
    mfma_allm<4, 2>(bufB_hi, bufB_lo, 136, w2h, w2l, 136, b2, w * 32, lane, acc);
    store_allm<2>(acc, w * 32, bufA_hi, bufA_lo, 168, lane);
  }
  __syncthreads();
  {  // L3: K=128, N=256; n-slice [w*64, w*64+64) + pool
    f32x4 acc[4][4];
    mfma_allm<4, 4>(bufA_hi, bufA_lo, 168, w3h, w3l, 136, b3, w * 64, lane, acc);
    outpool_allm<4>(acc, w * 64, out + (size_t)bs * 256, nvalid, lane);
  }
}

// ---------------------------------------------------------------------------
// Global SA (MFMA): MLP 259->256->512->1024, 16 points/block, wave=n-quarter.
// ---------------------------------------------------------------------------
__global__ __launch_bounds__(256, 2) void gsa_kernel(
    const float* __restrict__ x2,  // [16][256][256]
    const float* __restrict__ p2,  // [16][256][3]
    const unsigned short* __restrict__ g1h, const unsigned short* __restrict__ g1l,
    const unsigned short* __restrict__ g2h, const unsigned short* __restrict__ g2l,
    const unsigned short* __restrict__ g3h, const unsigned short* __restrict__ g3l,
    const float* __restrict__ b1, const float* __restrict__ b2,
    const float* __restrict__ b3,
    float* __restrict__ part)      // [16][16][1024]
{
  const int blk = blockIdx.x;  // 256
  const int bt = blk >> 4, gidx = blk & 15;
  const int tid = threadIdx.x;
  const int w = tid >> 6, lane = tid & 63;
  const int p0 = gidx * 16;
  __shared__ __align__(16) unsigned short inH[16 * 296], inL[16 * 296];
  __shared__ __align__(16) unsigned short h1H[16 * 264], h1L[16 * 264];
  __shared__ __align__(16) unsigned short h2H[16 * 520], h2L[16 * 520];
  {  // stage 16 points x 256 feats + 3 pos + zero pad to 288
    int p = tid >> 4, seg = tid & 15;
    const float* xr = x2 + ((size_t)(bt * 256 + p0 + p)) * 256 + seg * 16;
#pragma unroll
    for (int g = 0; g < 4; ++g) {
      float4 v = *(const float4*)(xr + 4 * g);
      float vv[4] = {v.x, v.y, v.z, v.w};
#pragma unroll
      for (int e = 0; e < 4; ++e) {
        unsigned short h, l;
        split_bf(vv[e], h, l);
        int k = seg * 16 + 4 * g + e;
        inH[p * 296 + k] = h;
        inL[p * 296 + k] = l;
      }
    }
    if (tid < 16) {
      const float* pr = p2 + (bt * 256 + p0 + tid) * 3;
#pragma unroll
      for (int c = 0; c < 3; ++c) {
        unsigned short h, l;
        split_bf(pr[c], h, l);
        inH[tid * 296 + 256 + c] = h;
        inL[tid * 296 + 256 + c] = l;
      }
      for (int k = 259; k < 288; ++k) {
        inH[tid * 296 + k] = 0;
        inL[tid * 296 + k] = 0;
      }
    }
  }
  __syncthreads();
  {  // L1: K=288(259), N=256
    f32x4 acc[4];
    mfma_1m<9, 4>(inH, inL, 296, g1h, g1l, 296, b1, w * 64, lane, acc);
    store_1m<4>(acc, w * 64, h1H, h1L, 264, lane);
  }
  __syncthreads();
  {  // L2: K=256, N=512
    f32x4 acc[8];
    mfma_1m<8, 8>(h1H, h1L, 264, g2h, g2l, 264, b2, w * 128, lane, acc);
    store_1m<8>(acc, w * 128, h2H, h2L, 520, lane);
  }
  __syncthreads();
  {  // L3: K=512, N=1024 + max over 16 points
    f32x4 acc[16];
    mfma_1m<16, 16>(h2H, h2L, 520, g3h, g3l, 520, b3, w * 256, lane, acc);
    const int col = lane & 15;
    float* op = part + ((size_t)(bt * 16 + gidx)) * 1024 + w * 256;
#pragma unroll
    for (int t = 0; t < 16; ++t) {
      float m = -DEVINF;
#pragma unroll
      for (int r = 0; r < 4; ++r) m = fmaxf(m, fmaxf(acc[t][r], 0.f));
      m = fmaxf(m, __shfl_xor(m, 16, 64));
      m = fmaxf(m, __shfl_xor(m, 32, 64));
      if ((lane >> 4) == 0) op[t * 16 + col] = m;
    }
  }
}

// ---------------------------------------------------------------------------
// head1: gmax + l1 + l2 + l3. One block per B-row (16 blocks).
// ---------------------------------------------------------------------------
__global__ __launch_bounds__(256) void head1_kernel(
    const float* __restrict__ part,  // [16][16][1024]
    const float* __restrict__ l1w, const float* __restrict__ l1b,
    const float* __restrict__ l2w, const float* __restrict__ l2b,
    const float* __restrict__ l3w, const float* __restrict__ l3b,
    float* __restrict__ hC)          // [16][256]
{
  const int m = blockIdx.x;
  const int tid = threadIdx.x;
  __shared__ float gA[1024];
  __shared__ float hX[512];
  __shared__ float hY[256];
#pragma unroll
  for (int j = 0; j < 4; ++j) {
    int c = j * 256 + tid;
    float mx = -DEVINF;
#pragma unroll
    for (int t = 0; t < 16; ++t)
      mx = fmaxf(mx, part[((size_t)(m * 16 + t)) * 1024 + c]);
    gA[c] = mx;
  }
  __syncthreads();
  {  // l1: 1024 -> 512, relu
    float a0 = l1b[tid], a1 = l1b[tid + 256];
#pragma unroll 4
    for (int k = 0; k < 1024; ++k) {
      float v = gA[k];
      a0 = fmaf(v, l1w[(size_t)k * 512 + tid], a0);
      a1 = fmaf(v, l1w[(size_t)k * 512 + tid + 256], a1);
    }
    hX[tid] = fmaxf(a0, 0.f);
    hX[tid + 256] = fmaxf(a1, 0.f);
  }
  __syncthreads();
  {  // l2: 512 -> 256, relu
    float a = l2b[tid];
#pragma unroll 4
    for (int k = 0; k < 512; ++k) a = fmaf(hX[k], l2w[(size_t)k * 256 + tid], a);
    hY[tid] = fmaxf(a, 0.f);
  }
  __syncthreads();
  {  // l3: 256 -> 256, no relu
    float a = l3b[tid];
#pragma unroll 4
    for (int k = 0; k < 256; ++k) a = fmaf(hY[k], l3w[(size_t)k * 256 + tid], a);
    hC[(size_t)m * 256 + tid] = a;
  }
}

// ---------------------------------------------------------------------------
// head2: fusion MLP (fw1,fw2,fw3) + l4 + l5. One block per fused row (4).
// ---------------------------------------------------------------------------
__global__ __launch_bounds__(256) void head2_kernel(
    const float* __restrict__ hC,  // [4][1024]
    const float* __restrict__ fw1, const float* __restrict__ fb1,
    const float* __restrict__ fw2, const float* __restrict__ fb2,
    const float* __restrict__ fw3, const float* __restrict__ fb3,
    const float* __restrict__ l4w, const float* __restrict__ l4b,
    const float* __restrict__ l5w, const float* __restrict__ l5b,
    float* __restrict__ out)       // [4][128]
{
  const int m = blockIdx.x;
  const int tid = threadIdx.x;
  __shared__ float A[1024];
  __shared__ float Bf[512];
#pragma unroll
  for (int j = 0; j < 4; ++j) A[j * 256 + tid] = hC[(size_t)m * 1024 + j * 256 + tid];
  __syncthreads();
  {  // fw1: 1024 -> 512 relu, A -> Bf
    float a0 = fb1[tid], a1 = fb1[tid + 256];
#pragma unroll 4
    for (int k = 0; k < 1024; ++k) {
      float v = A[k];
      a0 = fmaf(v, fw1[(size_t)k * 512 + tid], a0);
      a1 = fmaf(v, fw1[(size_t)k * 512 + tid + 256], a1);
    }
    Bf[tid] = fmaxf(a0, 0.f);
    Bf[tid + 256] = fmaxf(a1, 0.f);
  }
  __syncthreads();
  {  // fw2: 512 -> 512 relu, Bf -> A
    float a0 = fb2[tid], a1 = fb2[tid + 256];
#pragma unroll 4
    for (int k = 0; k < 512; ++k) {
      float v = Bf[k];
      a0 = fmaf(v, fw2[(size_t)k * 512 + tid], a0);
      a1 = fmaf(v, fw2[(size_t)k * 512 + tid + 256], a1);
    }
    __syncthreads();
    A[tid] = fmaxf(a0, 0.f);
    A[tid + 256] = fmaxf(a1, 0.f);
  }
  __syncthreads();
  {  // fw3: 512 -> 256 relu, A -> Bf
    float a = fb3[tid];
#pragma unroll 4
    for (int k = 0; k < 512; ++k) a = fmaf(A[k], fw3[(size_t)k * 256 + tid], a);
    __syncthreads();
    Bf[tid] = fmaxf(a, 0.f);
  }
  __syncthreads();
  {  // l4: 256 -> 128 relu, Bf -> A
    if (tid < 128) {
      float a = l4b[tid];
#pragma unroll 4
      for (int k = 0; k < 256; ++k) a = fmaf(Bf[k], l4w[(size_t)k * 128 + tid], a);
      A[tid] = fmaxf(a, 0.f);
    }
  }
  __syncthreads();
  {  // l5: 128 -> 128, A -> out
    if (tid < 128) {
      float a = l5b[tid];
#pragma unroll 4
      for (int k = 0; k < 128; ++k) a = fmaf(A[k], l5w[(size_t)k * 128 + tid], a);
      out[(size_t)m * 128 + tid] = a;
    }
  }
}

// ---------------------------------------------------------------------------
extern "C" void kernel_launch(void* const* d_in, const int* in_sizes, int n_in,
                              void* d_out, int out_size, void* d_ws, size_t ws_size,
                              hipStream_t stream) {
  (void)in_sizes; (void)n_in; (void)out_size; (void)ws_size;
  const float* x    = (const float*)d_in[0];
  const float* pos  = (const float*)d_in[1];
  const float* s1w1 = (const float*)d_in[2];  const float* s1b1 = (const float*)d_in[3];
  const float* s1w2 = (const float*)d_in[4];  const float* s1b2 = (const float*)d_in[5];
  const float* s1w3 = (const float*)d_in[6];  const float* s1b3 = (const float*)d_in[7];
  const float* s2w1 = (const float*)d_in[8];  const float* s2b1 = (const float*)d_in[9];
  const float* s2w2 = (const float*)d_in[10]; const float* s2b2 = (const float*)d_in[11];
  const float* s2w3 = (const float*)d_in[12]; const float* s2b3 = (const float*)d_in[13];
  const float* s3w1 = (const float*)d_in[14]; const float* s3b1 = (const float*)d_in[15];
  const float* s3w2 = (const float*)d_in[16]; const float* s3b2 = (const float*)d_in[17];
  const float* s3w3 = (const float*)d_in[18]; const float* s3b3 = (const float*)d_in[19];
  const float* fw1  = (const float*)d_in[20]; const float* fb1  = (const float*)d_in[21];
  const float* fw2  = (const float*)d_in[22]; const float* fb2  = (const float*)d_in[23];
  const float* fw3  = (const float*)d_in[24]; const float* fb3  = (const float*)d_in[25];
  const float* l1w  = (const float*)d_in[26]; const float* l1b  = (const float*)d_in[27];
  const float* l2w  = (const float*)d_in[28]; const float* l2b  = (const float*)d_in[29];
  const float* l3w  = (const float*)d_in[30]; const float* l3b  = (const float*)d_in[31];
  const float* l4w  = (const float*)d_in[32]; const float* l4b  = (const float*)d_in[33];
  const float* l5w  = (const float*)d_in[34]; const float* l5b  = (const float*)d_in[35];
  float* out = (float*)d_out;

  float* ws = (float*)d_ws;
  float* p1   = ws;                  // 16*1024*3
  float* x1   = p1 + 49152;          // 16*1024*128
  float* p2   = x1 + 2097152;        // 16*256*3
  float* x2   = p2 + 12288;          // 16*256*256
  float* part = x2 + 1048576;        // 16*16*1024
  float* hC   = part + 262144;       // 16*256
  // bf16 hi/lo transposed weight planes (u16)
  unsigned short* wp = (unsigned short*)(hC + 4096);
  unsigned short* s1w1h = wp;              unsigned short* s1w1l = s1w1h + 2560;    // [64][40]
  unsigned short* s1w2h = s1w1l + 2560;    unsigned short* s1w2l = s1w2h + 4608;    // [64][72]
  unsigned short* s1w3h = s1w2l + 4608;    unsigned short* s1w3l = s1w3h + 9216;    // [128][72]
  unsigned short* s2w1h = s1w3l + 9216;    unsigned short* s2w1l = s2w1h + 21504;   // [128][168]
  unsigned short* s2w2h = s2w1l + 21504;   unsigned short* s2w2l = s2w2h + 17408;   // [128][136]
  unsigned short* s2w3h = s2w2l + 17408;   unsigned short* s2w3l = s2w3h + 34816;   // [256][136]
  unsigned short* g1h   = s2w3l + 34816;   unsigned short* g1l   = g1h + 75776;     // [256][296]
  unsigned short* g2h   = g1l + 75776;     unsigned short* g2l   = g2h + 135168;    // [512][264]
  unsigned short* g3h   = g2l + 135168;    unsigned short* g3l   = g3h + 532480;    // [1024][520]

  PrepJobs jb;
  const float* srcs[9] = {s1w1, s1w2, s1w3, s2w1, s2w2, s2w3, s3w1, s3w2, s3w3};
  unsigned short* his[9] = {s1w1h, s1w2h, s1w3h, s2w1h, s2w2h, s2w3h, g1h, g2h, g3h};
  unsigned short* los[9] = {s1w1l, s1w2l, s1w3l, s2w1l, s2w2l, s2w3l, g1l, g2l, g3l};
  int Ks[9]  = {12, 64, 64, 131, 128, 128, 259, 256, 512};
  int Ns[9]  = {64, 64, 128, 128, 128, 256, 256, 512, 1024};
  int rls[9] = {40, 72, 72, 168, 136, 136, 296, 264, 520};
  int acc_blk = 0;
  for (int j = 0; j < 9; ++j) {
    jb.src[j] = srcs[j]; jb.hi[j] = his[j]; jb.lo[j] = los[j];
    jb.K[j] = Ks[j]; jb.N[j] = Ns[j]; jb.rl[j] = rls[j];
    jb.blk0[j] = acc_blk;
    acc_blk += (Ns[j] * rls[j] + 255) / 256;   // 256-thread granularity
  }
  jb.blk0[9] = acc_blk;

  fps1_prep_kernel<<<16 + acc_blk, 256, 0, stream>>>(pos, p1, jb);
  sa1_kernel<<<16 * 1024 + 16, 256, 0, stream>>>(x, pos, p1, p2, s1w1h, s1w1l,
                                                 s1w2h, s1w2l, s1w3h, s1w3l,
                                                 s1b1, s1b2, s1b3, x1);
  sa2_kernel<<<16 * 256, 256, 0, stream>>>(x1, p1, p2, s2w1h, s2w1l, s2w2h,
                                           s2w2l, s2w3h, s2w3l, s2b1, s2b2,
                                           s2b3, x2);
  gsa_kernel<<<256, 256, 0, stream>>>(x2, p2, g1h, g1l, g2h, g2l, g3h, g3l,
                                      s3b1, s3b2, s3b3, part);
  head1_kernel<<<16, 256, 0, stream>>>(part, l1w, l1b, l2w, l2b, l3w, l3b, hC);
  head2_kernel<<<4, 256, 0, stream>>>(hC, fw1, fb1, fw2, fb2, fw3, fb3, l4w,
                                      l4b, l5w, l5b, out);
}

// Round 12
// 1383.786 us; speedup vs baseline: 1.1458x; 1.0828x over previous
//
#include <hip/hip_runtime.h>
#include <cstddef>

#define DEVINF __builtin_inff()

typedef __attribute__((ext_vector_type(8))) short bf16x8;
typedef __attribute__((ext_vector_type(4))) float f32x4;
typedef __attribute__((ext_vector_type(2))) float f32x2;

__device__ __forceinline__ unsigned short f2bf(float x) {
  unsigned u = __float_as_uint(x);
  return (unsigned short)((u + 0x7fff + ((u >> 16) & 1)) >> 16);
}
__device__ __forceinline__ float bf2f(unsigned short h) {
  return __uint_as_float(((unsigned)h) << 16);
}
__device__ __forceinline__ void split_bf(float x, unsigned short& hi, unsigned short& lo) {
  hi = f2bf(x);
  lo = f2bf(x - bf2f(hi));
}

// ---------------------------------------------------------------------------
// FPS cooperative step (round-9 form — fastest measured): per-wave update,
// DPP ladder to lane 63, LDS key exchange. Key = (val_bits<<32)|~idx.
// ---------------------------------------------------------------------------
#define FPS_RED_LEVEL(CTRL)                                                      \
  {                                                                              \
    int th = __builtin_amdgcn_update_dpp((int)hi, (int)hi, CTRL, 0xf, 0xf, false); \
    int tl = __builtin_amdgcn_update_dpp((int)lo, (int)lo, CTRL, 0xf, 0xf, false); \
    bool take = ((unsigned)th > hi) || (((unsigned)th == hi) && ((unsigned)tl > lo)); \
    hi = take ? (unsigned)th : hi;                                               \
    lo = take ? (unsigned)tl : lo;                                               \
  }

template <int PPLH, int NCH>
__device__ __forceinline__ unsigned long long fps_wave_step(
    f32x2* qx, f32x2* qy, f32x2* qz, f32x2* d, float lx, float ly, float lz,
    int lane, int ibase) {
#pragma clang fp contract(off)
  const int CH = PPLH / NCH;
  float bv[NCH];
  int bi[NCH];
#pragma unroll
  for (int c = 0; c < NCH; ++c) { bv[c] = -DEVINF; bi[c] = 0x7fffffff; }
  f32x2 lxv = {lx, lx}, lyv = {ly, ly}, lzv = {lz, lz};
#pragma unroll
  for (int h = 0; h < PPLH; ++h) {
    const int c = h / CH;
    f32x2 dx = qx[h] - lxv, dy = qy[h] - lyv, dz = qz[h] - lzv;
    f32x2 t0 = dx * dx, t1 = dy * dy, t2 = dz * dz;
    f32x2 d2 = (t0 + t1) + t2;
    f32x2 dn;
    dn.x = fminf(d[h].x, d2.x);
    dn.y = fminf(d[h].y, d2.y);
    d[h] = dn;
    int i0 = ibase + (2 * h) * 64 + lane;
    if (dn.x > bv[c]) { bv[c] = dn.x; bi[c] = i0; }
    if (dn.y > bv[c]) { bv[c] = dn.y; bi[c] = i0 + 64; }
  }
  unsigned hi, lo;
  if (NCH == 4) {
    unsigned h0 = __float_as_uint(bv[0]), l0 = ~(unsigned)bi[0];
    unsigned h1 = __float_as_uint(bv[1]), l1 = ~(unsigned)bi[1];
    unsigned h2 = __float_as_uint(bv[2]), l2 = ~(unsigned)bi[2];
    unsigned h3 = __float_as_uint(bv[3]), l3 = ~(unsigned)bi[3];
    bool t01 = (h1 > h0) || ((h1 == h0) && (l1 > l0));
    unsigned ha = t01 ? h1 : h0, la = t01 ? l1 : l0;
    bool t23 = (h3 > h2) || ((h3 == h2) && (l3 > l2));
    unsigned hb = t23 ? h3 : h2, lb = t23 ? l3 : l2;
    bool tab = (hb > ha) || ((hb == ha) && (lb > la));
    hi = tab ? hb : ha;
    lo = tab ? lb : la;
  } else {
    const int c1 = (NCH > 1) ? 1 : 0;
    unsigned h0 = __float_as_uint(bv[0]), l0 = ~(unsigned)bi[0];
    unsigned h1 = __float_as_uint(bv[c1]), l1 = ~(unsigned)bi[c1];
    bool t01 = (h1 > h0) || ((h1 == h0) && (l1 > l0));
    hi = t01 ? h1 : h0;
    lo = t01 ? l1 : l0;
  }
  FPS_RED_LEVEL(0x111)  // row_shr:1
  FPS_RED_LEVEL(0x112)  // row_shr:2
  FPS_RED_LEVEL(0x114)  // row_shr:4
  FPS_RED_LEVEL(0x118)  // row_shr:8
  FPS_RED_LEVEL(0x142)  // row_bcast:15
  FPS_RED_LEVEL(0x143)  // row_bcast:31
  return (((unsigned long long)hi) << 32) | lo;  // valid on lane 63
}

// ---------------------------------------------------------------------------
// prep jobs table (weight transposes fused into fps1 launch, 256-granular).
// ---------------------------------------------------------------------------
struct PrepJobs {
  const float* src[9];
  unsigned short* hi[9];
  unsigned short* lo[9];
  int K[9], N[9], rl[9];
  int blk0[10];
};

// ---------------------------------------------------------------------------
// fps1 (blocks 0..15): 2048 -> 1024 centers, 4-wave cooperative (round-9
// form: post-barrier p4[last] read). blocks 16..: weight prep.
// ---------------------------------------------------------------------------
__global__ __launch_bounds__(256, 1) void fps1_prep_kernel(
    const float* __restrict__ pos, float* __restrict__ p1, PrepJobs jb) {
#pragma clang fp contract(off)
  const int tid = threadIdx.x;
  if (blockIdx.x >= 16) {
    int blk = blockIdx.x - 16;
    int j = 0;
#pragma unroll
    for (int t = 1; t < 9; ++t)
      if (blk >= jb.blk0[t]) j = t;
    int idx = (blk - jb.blk0[j]) * 256 + tid;
    int rl = jb.rl[j], N = jb.N[j], K = jb.K[j];
    if (idx >= N * rl) return;
    int n = idx / rl, k = idx - n * rl;
    float v = (k < K) ? jb.src[j][(size_t)k * N + n] : 0.f;
    unsigned short h, l;
    split_bf(v, h, l);
    jb.hi[j][idx] = h;
    jb.lo[j][idx] = l;
    return;
  }
  const int b = blockIdx.x;
  const int w = tid >> 6, lane = tid & 63;
  __shared__ __align__(16) float4 p4[2048];
  __shared__ __align__(16) float4 carr[1024];
  __shared__ unsigned long long kv[2][4];
  f32x2 qx[4], qy[4], qz[4], d[4];
  const int ibase = w * 512;
#pragma unroll
  for (int h = 0; h < 4; ++h) {
    int i0 = ibase + (2 * h) * 64 + lane, i1 = i0 + 64;
    const float* a = pos + ((size_t)b * 2048 + i0) * 3;
    const float* c = pos + ((size_t)b * 2048 + i1) * 3;
    float x0 = a[0], y0 = a[1], z0 = a[2];
    float x1 = c[0], y1 = c[1], z1 = c[2];
    qx[h].x = x0; qx[h].y = x1;
    qy[h].x = y0; qy[h].y = y1;
    qz[h].x = z0; qz[h].y = z1;
    d[h].x = DEVINF; d[h].y = DEVINF;
    p4[i0] = float4{x0, y0, z0, 0.f};
    p4[i1] = float4{x1, y1, z1, 0.f};
  }
  __syncthreads();
  int last = 0;
  for (int s = 0; s < 1024; ++s) {
    float4 c4 = p4[last];
    if (tid == 0) carr[s] = c4;
    unsigned long long k =
        fps_wave_step<4, 4>(qx, qy, qz, d, c4.x, c4.y, c4.z, lane, ibase);
    if (lane == 63) kv[s & 1][w] = k;
    __syncthreads();
    unsigned long long k0 = kv[s & 1][0], k1 = kv[s & 1][1];
    unsigned long long k2 = kv[s & 1][2], k3 = kv[s & 1][3];
    unsigned long long ka = k0 > k1 ? k0 : k1;
    unsigned long long kb = k2 > k3 ? k2 : k3;
    unsigned long long kk = ka > kb ? ka : kb;
    last = (int)~(unsigned)kk;
  }
  for (int i = tid; i < 1024; i += 256) {
    float4 c = carr[i];
    p1[((size_t)b * 1024 + i) * 3 + 0] = c.x;
    p1[((size_t)b * 1024 + i) * 3 + 1] = c.y;
    p1[((size_t)b * 1024 + i) * 3 + 2] = c.z;
  }
}

// ---------------------------------------------------------------------------
// MFMA building blocks — B fragments SOFTWARE-PIPELINED one (ks,t) step ahead
// (double-buffered regs, clamped unconditional prefetch address) so the
// ~200-300 cyc L2 latency is covered by the previous step's MFMAs.
// Same MFMA order/operands -> bit-identical results.
// ---------------------------------------------------------------------------
template <int KS, int T>
__device__ __forceinline__ void mfma_allm(
    const unsigned short* __restrict__ inHi, const unsigned short* __restrict__ inLo,
    int sIn, const unsigned short* __restrict__ wHi,
    const unsigned short* __restrict__ wLo, int rl, const float* __restrict__ bias,
    int n0, int lane, f32x4 acc[4][T]) {
  const int col = lane & 15, quad = lane >> 4;
#pragma unroll
  for (int t = 0; t < T; ++t) {
    float bv = bias[n0 + t * 16 + col];
#pragma unroll
    for (int mt = 0; mt < 4; ++mt) {
      acc[mt][t].x = bv; acc[mt][t].y = bv; acc[mt][t].z = bv; acc[mt][t].w = bv;
    }
  }
  size_t b0 = (size_t)(n0 + col) * rl + quad * 8;
  bf16x8 bh = *(const bf16x8*)(wHi + b0);
  bf16x8 bl = *(const bf16x8*)(wLo + b0);
#pragma unroll 1
  for (int ks = 0; ks < KS; ++ks) {
    bf16x8 ah[4], al[4];
#pragma unroll
    for (int mt = 0; mt < 4; ++mt) {
      int aoff = (mt * 16 + col) * sIn + ks * 32 + quad * 8;
      ah[mt] = *(const bf16x8*)(inHi + aoff);
      al[mt] = *(const bf16x8*)(inLo + aoff);
    }
#pragma unroll
    for (int t = 0; t < T; ++t) {
      int nks = (t + 1 < T) ? ks : ks + 1;
      int nt = (t + 1 < T) ? t + 1 : 0;
      if (nks > KS - 1) nks = KS - 1;  // clamp: value unused on last step
      size_t nboff = (size_t)(n0 + nt * 16 + col) * rl + nks * 32 + quad * 8;
      bf16x8 nh = *(const bf16x8*)(wHi + nboff);
      bf16x8 nl = *(const bf16x8*)(wLo + nboff);
#pragma unroll
      for (int mt = 0; mt < 4; ++mt) {
        acc[mt][t] = __builtin_amdgcn_mfma_f32_16x16x32_bf16(ah[mt], bh, acc[mt][t], 0, 0, 0);
        acc[mt][t] = __builtin_amdgcn_mfma_f32_16x16x32_bf16(ah[mt], bl, acc[mt][t], 0, 0, 0);
        acc[mt][t] = __builtin_amdgcn_mfma_f32_16x16x32_bf16(al[mt], bh, acc[mt][t], 0, 0, 0);
      }
      bh = nh;
      bl = nl;
    }
  }
}

template <int T>
__device__ __forceinline__ void store_allm(const f32x4 acc[4][T], int n0,
                                           unsigned short* outHi,
                                           unsigned short* outLo, int sOut,
                                           int lane) {
  const int col = lane & 15, quad = lane >> 4;
#pragma unroll
  for (int mt = 0; mt < 4; ++mt)
#pragma unroll
    for (int t = 0; t < T; ++t)
#pragma unroll
      for (int r = 0; r < 4; ++r) {
        int edge = mt * 16 + quad * 4 + r;
        float v = fmaxf(acc[mt][t][r], 0.f);
        unsigned short h, l;
        split_bf(v, h, l);
        outHi[edge * sOut + n0 + t * 16 + col] = h;
        outLo[edge * sOut + n0 + t * 16 + col] = l;
      }
}

template <int T>
__device__ __forceinline__ void outpool_allm(const f32x4 acc[4][T], int n0,
                                             float* __restrict__ outp, int nvalid,
                                             int lane) {
  const int col = lane & 15, quad = lane >> 4;
#pragma unroll
  for (int t = 0; t < T; ++t) {
    float m = -DEVINF;
#pragma unroll
    for (int mt = 0; mt < 4; ++mt)
#pragma unroll
      for (int r = 0; r < 4; ++r) {
        int edge = mt * 16 + quad * 4 + r;
        float v = fmaxf(acc[mt][t][r], 0.f);
        if (edge >= nvalid) v = -DEVINF;
        m = fmaxf(m, v);
      }
    m = fmaxf(m, __shfl_xor(m, 16, 64));
    m = fmaxf(m, __shfl_xor(m, 32, 64));
    if (quad == 0) outp[n0 + t * 16 + col] = m;
  }
}

// single-m-tile variants (gsa), B-pipelined identically
template <int KS, int T>
__device__ __forceinline__ void mfma_1m(
    const unsigned short* __restrict__ inHi, const unsigned short* __restrict__ inLo,
    int sIn, const unsigned short* __restrict__ wHi,
    const unsigned short* __restrict__ wLo, int rl, const float* __restrict__ bias,
    int n0, int lane, f32x4 acc[T]) {
  const int col = lane & 15, quad = lane >> 4;
#pragma unroll
  for (int t = 0; t < T; ++t) {
    float bv = bias[n0 + t * 16 + col];
    acc[t].x = bv; acc[t].y = bv; acc[t].z = bv; acc[t].w = bv;
  }
  size_t b0 = (size_t)(n0 + col) * rl + quad * 8;
  bf16x8 bh = *(const bf16x8*)(wHi + b0);
  bf16x8 bl = *(const bf16x8*)(wLo + b0);
#pragma unroll 1
  for (int ks = 0; ks < KS; ++ks) {
    int aoff = col * sIn + ks * 32 + quad * 8;
    bf16x8 ah = *(const bf16x8*)(inHi + aoff);
    bf16x8 al = *(const bf16x8*)(inLo + aoff);
#pragma unroll
    for (int t = 0; t < T; ++t) {
      int nks = (t + 1 < T) ? ks : ks + 1;
      int nt = (t + 1 < T) ? t + 1 : 0;
      if (nks > KS - 1) nks = KS - 1;
      size_t nboff = (size_t)(n0 + nt * 16 + col) * rl + nks * 32 + quad * 8;
      bf16x8 nh = *(const bf16x8*)(wHi + nboff);
      bf16x8 nl = *(const bf16x8*)(wLo + nboff);
      acc[t] = __builtin_amdgcn_mfma_f32_16x16x32_bf16(ah, bh, acc[t], 0, 0, 0);
      acc[t] = __builtin_amdgcn_mfma_f32_16x16x32_bf16(ah, bl, acc[t], 0, 0, 0);
      acc[t] = __builtin_amdgcn_mfma_f32_16x16x32_bf16(al, bh, acc[t], 0, 0, 0);
      bh = nh;
      bl = nl;
    }
  }
}

template <int T>
__device__ __forceinline__ void store_1m(const f32x4 acc[T], int n0,
                                         unsigned short* outHi,
                                         unsigned short* outLo, int sOut, int lane) {
  const int col = lane & 15, quad = lane >> 4;
#pragma unroll
  for (int t = 0; t < T; ++t)
#pragma unroll
    for (int r = 0; r < 4; ++r) {
      int p = quad * 4 + r;
      float v = fmaxf(acc[t][r], 0.f);
      unsigned short h, l;
      split_bf(v, h, l);
      outHi[p * sOut + n0 + t * 16 + col] = h;
      outLo[p * sOut + n0 + t * 16 + col] = l;
    }
}

// ---------------------------------------------------------------------------
// SA1 (MFMA, wave=n-slice) + EMBEDDED fps2 (blocks 0..15, round-9 form).
// ---------------------------------------------------------------------------
__global__ __launch_bounds__(256, 4) void sa1_kernel(
    const float* __restrict__ x,    // [16][2048][9]
    const float* __restrict__ pos,  // [16][2048][3]
    const float* __restrict__ ctr,  // p1: [16][1024][3]
    float* __restrict__ p2,         // [16][256][3] (fps2 output)
    const unsigned short* __restrict__ w1h, const unsigned short* __restrict__ w1l,
    const unsigned short* __restrict__ w2h, const unsigned short* __restrict__ w2l,
    const unsigned short* __restrict__ w3h, const unsigned short* __restrict__ w3l,
    const float* __restrict__ b1, const float* __restrict__ b2,
    const float* __restrict__ b3,
    float* __restrict__ out)        // [16][1024][128]
{
  const int N = 2048;
  const float r2 = (float)(0.2 * 0.2);
  const int tid = threadIdx.x;
  const int w = tid >> 6, lane = tid & 63;
  __shared__ __align__(16) unsigned short smem[4 * 4608];  // 36,864 B
  unsigned short* bufA_hi = smem;
  unsigned short* bufA_lo = smem + 4608;
  unsigned short* bufB_hi = smem + 9216;
  unsigned short* bufB_lo = smem + 13824;
  __shared__ int nb[64];
  __shared__ int tot[4];
  __shared__ unsigned long long kv2[2][4];

  if (blockIdx.x < 16) {
    // ------------- fps2: 1024 -> 256 centers, 4-wave cooperative -------------
    const int bb = blockIdx.x;
    float4* q4 = (float4*)smem;              // bytes 0..16383
    float4* carr = (float4*)(smem + 8192);   // bytes 16384..20479
    for (int i = tid; i < 1024; i += 256) {
      const float* pr = ctr + ((size_t)bb * 1024 + i) * 3;
      q4[i] = float4{pr[0], pr[1], pr[2], 0.f};
    }
    __syncthreads();
    f32x2 qx[2], qy[2], qz[2], d[2];
    const int ibase = w * 256;
#pragma unroll
    for (int h = 0; h < 2; ++h) {
      int i0 = ibase + (2 * h) * 64 + lane, i1 = i0 + 64;
      float4 a = q4[i0], c = q4[i1];
      qx[h].x = a.x; qx[h].y = c.x;
      qy[h].x = a.y; qy[h].y = c.y;
      qz[h].x = a.z; qz[h].y = c.z;
      d[h].x = DEVINF; d[h].y = DEVINF;
    }
    int last = 0;
    for (int s = 0; s < 256; ++s) {
      float4 c4 = q4[last];
      if (tid == 0) carr[s] = c4;
      unsigned long long k =
          fps_wave_step<2, 2>(qx, qy, qz, d, c4.x, c4.y, c4.z, lane, ibase);
      if (lane == 63) kv2[s & 1][w] = k;
      __syncthreads();
      unsigned long long k0 = kv2[s & 1][0], k1 = kv2[s & 1][1];
      unsigned long long k2 = kv2[s & 1][2], k3 = kv2[s & 1][3];
      unsigned long long ka = k0 > k1 ? k0 : k1;
      unsigned long long kb = k2 > k3 ? k2 : k3;
      unsigned long long kk = ka > kb ? ka : kb;
      last = (int)~(unsigned)kk;
    }
    {
      float4 c = carr[tid];
      if (tid < 256) {
        p2[((size_t)bb * 256 + tid) * 3 + 0] = c.x;
        p2[((size_t)bb * 256 + tid) * 3 + 1] = c.y;
        p2[((size_t)bb * 256 + tid) * 3 + 2] = c.z;
      }
    }
    return;
  }

  const int bs = blockIdx.x - 16;
  const int b = bs >> 10;
  const float cx = ctr[bs * 3 + 0], cy = ctr[bs * 3 + 1], cz = ctr[bs * 3 + 2];
  // ---- ball query: masks in registers (wave w owns groups w*8..w*8+7) ----
  nb[lane] = 0;
  unsigned long long mloc[8];
  {
#pragma clang fp contract(off)
#pragma unroll
    for (int it = 0; it < 8; ++it) {
      int i = (w * 8 + it) * 64 + lane;
      const float* p = pos + ((size_t)b * N + i) * 3;
      float dx = p[0] - cx, dy = p[1] - cy, dz = p[2] - cz;
      float t0 = dx * dx, t1 = dy * dy, t2 = dz * dz;
      float d2 = (t0 + t1) + t2;
      mloc[it] = __ballot(d2 <= r2);
    }
  }
  {
    int mytot = 0;
#pragma unroll
    for (int it = 0; it < 8; ++it) mytot += (int)__popcll(mloc[it]);
    if (lane == 0) tot[w] = mytot;
  }
  __syncthreads();
  const int t0s = tot[0], t1s = tot[1], t2s = tot[2], t3s = tot[3];
  {
    int cnt = (w > 0 ? t0s : 0) + (w > 1 ? t1s : 0) + (w > 2 ? t2s : 0);
#pragma unroll
    for (int it = 0; it < 8; ++it) {
      unsigned long long m = mloc[it];
      bool inr = (m >> lane) & 1;
      int posn = cnt + (int)__popcll(m & ((1ull << lane) - 1ull));
      if (inr && posn < 64) nb[posn] = (w * 8 + it) * 64 + lane;
      cnt += (int)__popcll(m);
    }
  }
  const int total = t0s + t1s + t2s + t3s;
  const int nvalid = total < 64 ? total : 64;
  __syncthreads();  // nb complete & visible
  // ---- feature staging split across waves: w0..w2 -> x feats, w3 -> rel+pad
  {
    int j = nb[lane];
    if (w < 3) {
      const float* xr = x + ((size_t)b * N + j) * 9 + w * 3;
      float f0 = xr[0], f1 = xr[1], f2 = xr[2];
      unsigned short h, l;
      split_bf(f0, h, l); bufA_hi[lane * 72 + w * 3 + 0] = h; bufA_lo[lane * 72 + w * 3 + 0] = l;
      split_bf(f1, h, l); bufA_hi[lane * 72 + w * 3 + 1] = h; bufA_lo[lane * 72 + w * 3 + 1] = l;
      split_bf(f2, h, l); bufA_hi[lane * 72 + w * 3 + 2] = h; bufA_lo[lane * 72 + w * 3 + 2] = l;
    } else {
      const float* pr = pos + ((size_t)b * N + j) * 3;
      float rr[3] = {pr[0] - cx, pr[1] - cy, pr[2] - cz};
#pragma unroll
      for (int c = 0; c < 3; ++c) {
        unsigned short h, l;
        split_bf(rr[c], h, l);
        bufA_hi[lane * 72 + 9 + c] = h;
        bufA_lo[lane * 72 + 9 + c] = l;
      }
#pragma unroll
      for (int k = 12; k < 32; ++k) {
        bufA_hi[lane * 72 + k] = 0;
        bufA_lo[lane * 72 + k] = 0;
      }
    }
  }
  __syncthreads();
  {  // L1: K=32(12), N=64; wave n-slice [w*16, w*16+16)
    f32x4 acc[4][1];
    mfma_allm<1, 1>(bufA_hi, bufA_lo, 72, w1h, w1l, 40, b1, w * 16, lane, acc);
    store_allm<1>(acc, w * 16, bufB_hi, bufB_lo, 72, lane);
  }
  __syncthreads();
  {  // L2: K=64, N=64; reads B, writes A
    f32x4 acc[4][1];
    mfma_allm<2, 1>(bufB_hi, bufB_lo, 72, w2h, w2l, 72, b2, w * 16, lane, acc);
    store_allm<1>(acc, w * 16, bufA_hi, bufA_lo, 72, lane);
  }
  __syncthreads();
  {  // L3: K=64, N=128; wave n-slice [w*32, w*32+32) + pool
    f32x4 acc[4][2];
    mfma_allm<2, 2>(bufA_hi, bufA_lo, 72, w3h, w3l, 72, b3, w * 32, lane, acc);
    outpool_allm<2>(acc, w * 32, out + (size_t)bs * 128, nvalid, lane);
  }
}

// ---------------------------------------------------------------------------
// SA2 (MFMA, wave=n-slice): register-mask ball query + MLP + maxpool.
// ---------------------------------------------------------------------------
__global__ __launch_bounds__(256, 2) void sa2_kernel(
    const float* __restrict__ x1,   // [16][1024][128]
    const float* __restrict__ pos1, // [16][1024][3]
    const float* __restrict__ ctr,  // [16][256][3]
    const unsigned short* __restrict__ w1h, const unsigned short* __restrict__ w1l,
    const unsigned short* __restrict__ w2h, const unsigned short* __restrict__ w2l,
    const unsigned short* __restrict__ w3h, const unsigned short* __restrict__ w3l,
    const float* __restrict__ b1, const float* __restrict__ b2,
    const float* __restrict__ b3,
    float* __restrict__ out)        // [16][256][256]
{
  const int N = 1024;
  const float r2 = (float)(0.4 * 0.4);
  const int bs = blockIdx.x;
  const int b = bs >> 8;
  const int tid = threadIdx.x;
  const int w = tid >> 6, lane = tid & 63;
  const float cx = ctr[bs * 3 + 0], cy = ctr[bs * 3 + 1], cz = ctr[bs * 3 + 2];
  __shared__ __align__(16) unsigned short bufA_hi[64 * 168], bufA_lo[64 * 168];
  __shared__ __align__(16) unsigned short bufB_hi[64 * 136], bufB_lo[64 * 136];
  __shared__ int nb[64];
  __shared__ int tot[4];
  nb[lane] = 0;
  unsigned long long mloc[4];
  {
#pragma clang fp contract(off)
#pragma unroll
    for (int it = 0; it < 4; ++it) {
      int i = (w * 4 + it) * 64 + lane;
      const float* p = pos1 + ((size_t)b * N + i) * 3;
      float dx = p[0] - cx, dy = p[1] - cy, dz = p[2] - cz;
      float t0 = dx * dx, t1 = dy * dy, t2 = dz * dz;
      float d2 = (t0 + t1) + t2;
      mloc[it] = __ballot(d2 <= r2);
    }
  }
  {
    int mytot = 0;
#pragma unroll
    for (int it = 0; it < 4; ++it) mytot += (int)__popcll(mloc[it]);
    if (lane == 0) tot[w] = mytot;
  }
  __syncthreads();
  const int t0s = tot[0], t1s = tot[1], t2s = tot[2], t3s = tot[3];
  {
    int cnt = (w > 0 ? t0s : 0) + (w > 1 ? t1s : 0) + (w > 2 ? t2s : 0);
#pragma unroll
    for (int it = 0; it < 4; ++it) {
      unsigned long long m = mloc[it];
      bool inr = (m >> lane) & 1;
      int posn = cnt + (int)__popcll(m & ((1ull << lane) - 1ull));
      if (inr && posn < 64) nb[posn] = (w * 4 + it) * 64 + lane;
      cnt += (int)__popcll(m);
    }
  }
  const int total = t0s + t1s + t2s + t3s;
  const int nvalid = total < 64 ? total : 64;
  __syncthreads();  // nb complete & visible
  {  // stage features: quarter w loads k in [32w, 32w+32); w0 also rel+pad
    int j = nb[lane];
    const float* xr = x1 + ((size_t)b * N + j) * 128 + 32 * w;
#pragma unroll
    for (int g = 0; g < 8; ++g) {
      float4 v = *(const float4*)(xr + 4 * g);
      float vv[4] = {v.x, v.y, v.z, v.w};
#pragma unroll
      for (int e = 0; e < 4; ++e) {
        unsigned short h, l;
        split_bf(vv[e], h, l);
        int k = 32 * w + 4 * g + e;
        bufA_hi[lane * 168 + k] = h;
        bufA_lo[lane * 168 + k] = l;
      }
    }
    if (w == 0) {
      const float* pr = pos1 + ((size_t)b * N + j) * 3;
      float rr[3] = {pr[0] - cx, pr[1] - cy, pr[2] - cz};
#pragma unroll
      for (int c = 0; c < 3; ++c) {
        unsigned short h, l;
        split_bf(rr[c], h, l);
        bufA_hi[lane * 168 + 128 + c] = h;
        bufA_lo[lane * 168 + 128 + c] = l;
      }
#pragma unroll
      for (int k = 131; k < 160; ++k) {
        bufA_hi[lane * 168 + k] = 0;
        bufA_lo[lane * 168 + k] = 0;
      }
    }
  }
  __syncthreads();
  {  // L1: K=160(131), N=128; n-slice [w*32, w*32+32)
    f32x4 acc[4][2];
    mfma_allm<5, 2>(bufA_hi, bufA_lo, 168, w1h, w1l, 168, b1, w * 32, lane, acc);
    store_allm<2>(acc, w * 32, bufB_hi, bufB_lo, 136, lane);
  }
  __syncthreads();
  {  // L2: K=128, N=128; reads B, writes A
    f32x4 acc[4][2];
    mfma_allm<4, 2>(bufB_hi, bufB_lo, 136, w2h, w2l, 136, b2, w * 32, lane, acc);
    store_allm<2>(acc, w * 32, bufA_hi, bufA_lo, 168, lane);
  }
  __syncthreads();
  {  // L3: K=128, N=256; n-slice [w*64, w*64+64) + pool
    f32x4 acc[4][4];
    mfma_allm<4, 4>(bufA_hi, bufA_lo, 168, w3h, w3l, 136, b3, w * 64, lane, acc);
    outpool_allm<4>(acc, w * 64, out + (size_t)bs * 256, nvalid, lane);
  }
}

// ---------------------------------------------------------------------------
// Global SA (MFMA): MLP 259->256->512->1024, 16 points/block, wave=n-quarter.
// ---------------------------------------------------------------------------
__global__ __launch_bounds__(256, 2) void gsa_kernel(
    const float* __restrict__ x2,  // [16][256][256]
    const float* __restrict__ p2,  // [16][256][3]
    const unsigned short* __restrict__ g1h, const unsigned short* __restrict__ g1l,
    const unsigned short* __restrict__ g2h, const unsigned short* __restrict__ g2l,
    const unsigned short* __restrict__ g3h, const unsigned short* __restrict__ g3l,
    const float* __restrict__ b1, const float* __restrict__ b2,
    const float* __restrict__ b3,
    float* __restrict__ part)      // [16][16][1024]
{
  const int blk = blockIdx.x;  // 256
  const int bt = blk >> 4, gidx = blk & 15;
  const int tid = threadIdx.x;
  const int w = tid >> 6, lane = tid & 63;
  const int p0 = gidx * 16;
  __shared__ __align__(16) unsigned short inH[16 * 296], inL[16 * 296];
  __shared__ __align__(16) unsigned short h1H[16 * 264], h1L[16 * 264];
  __shared__ __align__(16) unsigned short h2H[16 * 520], h2L[16 * 520];
  {  // stage 16 points x 256 feats + 3 pos + zero pad to 288
    int p = tid >> 4, seg = tid & 15;
    const float* xr = x2 + ((size_t)(bt * 256 + p0 + p)) * 256 + seg * 16;
#pragma unroll
    for (int g = 0; g < 4; ++g) {
      float4 v = *(const float4*)(xr + 4 * g);
      float vv[4] = {v.x, v.y, v.z, v.w};
#pragma unroll
      for (int e = 0; e < 4; ++e) {
        unsigned short h, l;
        split_bf(vv[e], h, l);
        int k = seg * 16 + 4 * g + e;
        inH[p * 296 + k] = h;
        inL[p * 296 + k] = l;
      }
    }
    if (tid < 16) {
      const float* pr = p2 + (bt * 256 + p0 + tid) * 3;
#pragma unroll
      for (int c = 0; c < 3; ++c) {
        unsigned short h, l;
        split_bf(pr[c], h, l);
        inH[tid * 296 + 256 + c] = h;
        inL[tid * 296 + 256 + c] = l;
      }
      for (int k = 259; k < 288; ++k) {
        inH[tid * 296 + k] = 0;
        inL[tid * 296 + k] = 0;
      }
    }
  }
  __syncthreads();
  {  // L1: K=288(259), N=256
    f32x4 acc[4];
    mfma_1m<9, 4>(inH, inL, 296, g1h, g1l, 296, b1, w * 64, lane, acc);
    store_1m<4>(acc, w * 64, h1H, h1L, 264, lane);
  }
  __syncthreads();
  {  // L2: K=256, N=512
    f32x4 acc[8];
    mfma_1m<8, 8>(h1H, h1L, 264, g2h, g2l, 264, b2, w * 128, lane, acc);
    store_1m<8>(acc, w * 128, h2H, h2L, 520, lane);
  }
  __syncthreads();
  {  // L3: K=512, N=1024 + max over 16 points
    f32x4 acc[16];
    mfma_1m<16, 16>(h2H, h2L, 520, g3h, g3l, 520, b3, w * 256, lane, acc);
    const int col = lane & 15;
    float* op = part + ((size_t)(bt * 16 + gidx)) * 1024 + w * 256;
#pragma unroll
    for (int t = 0; t < 16; ++t) {
      float m = -DEVINF;
#pragma unroll
      for (int r = 0; r < 4; ++r) m = fmaxf(m, fmaxf(acc[t][r], 0.f));
      m = fmaxf(m, __shfl_xor(m, 16, 64));
      m = fmaxf(m, __shfl_xor(m, 32, 64));
      if ((lane >> 4) == 0) op[t * 16 + col] = m;
    }
  }
}

// ---------------------------------------------------------------------------
// head1: gmax + l1 + l2 + l3. One block per B-row (16 blocks).
// ---------------------------------------------------------------------------
__global__ __launch_bounds__(256) void head1_kernel(
    const float* __restrict__ part,  // [16][16][1024]
    const float* __restrict__ l1w, const float* __restrict__ l1b,
    const float* __restrict__ l2w, const float* __restrict__ l2b,
    const float* __restrict__ l3w, const float* __restrict__ l3b,
    float* __restrict__ hC)          // [16][256]
{
  const int m = blockIdx.x;
  const int tid = threadIdx.x;
  __shared__ float gA[1024];
  __shared__ float hX[512];
  __shared__ float hY[256];
#pragma unroll
  for (int j = 0; j < 4; ++j) {
    int c = j * 256 + tid;
    float mx = -DEVINF;
#pragma unroll
    for (int t = 0; t < 16; ++t)
      mx = fmaxf(mx, part[((size_t)(m * 16 + t)) * 1024 + c]);
    gA[c] = mx;
  }
  __syncthreads();
  {  // l1: 1024 -> 512, relu
    float a0 = l1b[tid], a1 = l1b[tid + 256];
#pragma unroll 4
    for (int k = 0; k < 1024; ++k) {
      float v = gA[k];
      a0 = fmaf(v, l1w[(size_t)k * 512 + tid], a0);
      a1 = fmaf(v, l1w[(size_t)k * 512 + tid + 256], a1);
    }
    hX[tid] = fmaxf(a0, 0.f);
    hX[tid + 256] = fmaxf(a1, 0.f);
  }
  __syncthreads();
  {  // l2: 512 -> 256, relu
    float a = l2b[tid];
#pragma unroll 4
    for (int k = 0; k < 512; ++k) a = fmaf(hX[k], l2w[(size_t)k * 256 + tid], a);
    hY[tid] = fmaxf(a, 0.f);
  }
  __syncthreads();
  {  // l3: 256 -> 256, no relu
    float a = l3b[tid];
#pragma unroll 4
    for (int k = 0; k < 256; ++k) a = fmaf(hY[k], l3w[(size_t)k * 256 + tid], a);
    hC[(size_t)m * 256 + tid] = a;
  }
}

// ---------------------------------------------------------------------------
// head2: fusion MLP (fw1,fw2,fw3) + l4 + l5. One block per fused row (4).
// ---------------------------------------------------------------------------
__global__ __launch_bounds__(256) void head2_kernel(
    const float* __restrict__ hC,  // [4][1024]
    const float* __restrict__ fw1, const float* __restrict__ fb1,
    const float* __restrict__ fw2, const float* __restrict__ fb2,
    const float* __restrict__ fw3, const float* __restrict__ fb3,
    const float* __restrict__ l4w, const float* __restrict__ l4b,
    const float* __restrict__ l5w, const float* __restrict__ l5b,
    float* __restrict__ out)       // [4][128]
{
  const int m = blockIdx.x;
  const int tid = threadIdx.x;
  __shared__ float A[1024];
  __shared__ float Bf[512];
#pragma unroll
  for (int j = 0; j < 4; ++j) A[j * 256 + tid] = hC[(size_t)m * 1024 + j * 256 + tid];
  __syncthreads();
  {  // fw1: 1024 -> 512 relu, A -> Bf
    float a0 = fb1[tid], a1 = fb1[tid + 256];
#pragma unroll 4
    for (int k = 0; k < 1024; ++k) {
      float v = A[k];
      a0 = fmaf(v, fw1[(size_t)k * 512 + tid], a0);
      a1 = fmaf(v, fw1[(size_t)k * 512 + tid + 256], a1);
    }
    Bf[tid] = fmaxf(a0, 0.f);
    Bf[tid + 256] = fmaxf(a1, 0.f);
  }
  __syncthreads();
  {  // fw2: 512 -> 512 relu, Bf -> A
    float a0 = fb2[tid], a1 = fb2[tid + 256];
#pragma unroll 4
    for (int k = 0; k < 512; ++k) {
      float v = Bf[k];
      a0 = fmaf(v, fw2[(size_t)k * 512 + tid], a0);
      a1 = fmaf(v, fw2[(size_t)k * 512 + tid + 256], a1);
    }
    __syncthreads();
    A[tid] = fmaxf(a0, 0.f);
    A[tid + 256] = fmaxf(a1, 0.f);
  }
  __syncthreads();
  {  // fw3: 512 -> 256 relu, A -> Bf
    float a = fb3[tid];
#pragma unroll 4
    for (int k = 0; k < 512; ++k) a = fmaf(A[k], fw3[(size_t)k * 256 + tid], a);
    __syncthreads();
    Bf[tid] = fmaxf(a, 0.f);
  }
  __syncthreads();
  {  // l4: 256 -> 128 relu, Bf -> A
    if (tid < 128) {
      float a = l4b[tid];
#pragma unroll 4
      for (int k = 0; k < 256; ++k) a = fmaf(Bf[k], l4w[(size_t)k * 128 + tid], a);
      A[tid] = fmaxf(a, 0.f);
    }
  }
  __syncthreads();
  {  // l5: 128 -> 128, A -> out
    if (tid < 128) {
      float a = l5b[tid];
#pragma unroll 4
      for (int k = 0; k < 128; ++k) a = fmaf(A[k], l5w[(size_t)k * 128 + tid], a);
      out[(size_t)m * 128 + tid] = a;
    }
  }
}

// ---------------------------------------------------------------------------
extern "C" void kernel_launch(void* const* d_in, const int* in_sizes, int n_in,
                              void* d_out, int out_size, void* d_ws, size_t ws_size,
                              hipStream_t stream) {
  (void)in_sizes; (void)n_in; (void)out_size; (void)ws_size;
  const float* x    = (const float*)d_in[0];
  const float* pos  = (const float*)d_in[1];
  const float* s1w1 = (const float*)d_in[2];  const float* s1b1 = (const float*)d_in[3];
  const float* s1w2 = (const float*)d_in[4];  const float* s1b2 = (const float*)d_in[5];
  const float* s1w3 = (const float*)d_in[6];  const float* s1b3 = (const float*)d_in[7];
  const float* s2w1 = (const float*)d_in[8];  const float* s2b1 = (const float*)d_in[9];
  const float* s2w2 = (const float*)d_in[10]; const float* s2b2 = (const float*)d_in[11];
  const float* s2w3 = (const float*)d_in[12]; const float* s2b3 = (const float*)d_in[13];
  const float* s3w1 = (const float*)d_in[14]; const float* s3b1 = (const float*)d_in[15];
  const float* s3w2 = (const float*)d_in[16]; const float* s3b2 = (const float*)d_in[17];
  const float* s3w3 = (const float*)d_in[18]; const float* s3b3 = (const float*)d_in[19];
  const float* fw1  = (const float*)d_in[20]; const float* fb1  = (const float*)d_in[21];
  const float* fw2  = (const float*)d_in[22]; const float* fb2  = (const float*)d_in[23];
  const float* fw3  = (const float*)d_in[24]; const float* fb3  = (const float*)d_in[25];
  const float* l1w  = (const float*)d_in[26]; const float* l1b  = (const float*)d_in[27];
  const float* l2w  = (const float*)d_in[28]; const float* l2b  = (const float*)d_in[29];
  const float* l3w  = (const float*)d_in[30]; const float* l3b  = (const float*)d_in[31];
  const float* l4w  = (const float*)d_in[32]; const float* l4b  = (const float*)d_in[33];
  const float* l5w  = (const float*)d_in[34]; const float* l5b  = (const float*)d_in[35];
  float* out = (float*)d_out;

  float* ws = (float*)d_ws;
  float* p1   = ws;                  // 16*1024*3
  float* x1   = p1 + 49152;          // 16*1024*128
  float* p2   = x1 + 2097152;        // 16*256*3
  float* x2   = p2 + 12288;          // 16*256*256
  float* part = x2 + 1048576;        // 16*16*1024
  float* hC   = part + 262144;       // 16*256
  // bf16 hi/lo transposed weight planes (u16)
  unsigned short* wp = (unsigned short*)(hC + 4096);
  unsigned short* s1w1h = wp;              unsigned short* s1w1l = s1w1h + 2560;    // [64][40]
  unsigned short* s1w2h = s1w1l + 2560;    unsigned short* s1w2l = s1w2h + 4608;    // [64][72]
  unsigned short* s1w3h = s1w2l + 4608;    unsigned short* s1w3l = s1w3h + 9216;    // [128][72]
  unsigned short* s2w1h = s1w3l + 9216;    unsigned short* s2w1l = s2w1h + 21504;   // [128][168]
  unsigned short* s2w2h = s2w1l + 21504;   unsigned short* s2w2l = s2w2h + 17408;   // [128][136]
  unsigned short* s2w3h = s2w2l + 17408;   unsigned short* s2w3l = s2w3h + 34816;   // [256][136]
  unsigned short* g1h   = s2w3l + 34816;   unsigned short* g1l   = g1h + 75776;     // [256][296]
  unsigned short* g2h   = g1l + 75776;     unsigned short* g2l   = g2h + 135168;    // [512][264]
  unsigned short* g3h   = g2l + 135168;    unsigned short* g3l   = g3h + 532480;    // [1024][520]

  PrepJobs jb;
  const float* srcs[9] = {s1w1, s1w2, s1w3, s2w1, s2w2, s2w3, s3w1, s3w2, s3w3};
  unsigned short* his[9] = {s1w1h, s1w2h, s1w3h, s2w1h, s2w2h, s2w3h, g1h, g2h, g3h};
  unsigned short* los[9] = {s1w1l, s1w2l, s1w3l, s2w1l, s2w2l, s2w3l, g1l, g2l, g3l};
  int Ks[9]  = {12, 64, 64, 131, 128, 128, 259, 256, 512};
  int Ns[9]  = {64, 64, 128, 128, 128, 256, 256, 512, 1024};
  int rls[9] = {40, 72, 72, 168, 136, 136, 296, 264, 520};
  int acc_blk = 0;
  for (int j = 0; j < 9; ++j) {
    jb.src[j] = srcs[j]; jb.hi[j] = his[j]; jb.lo[j] = los[j];
    jb.K[j] = Ks[j]; jb.N[j] = Ns[j]; jb.rl[j] = rls[j];
    jb.blk0[j] = acc_blk;
    acc_blk += (Ns[j] * rls[j] + 255) / 256;   // 256-thread granularity
  }
  jb.blk0[9] = acc_blk;

  fps1_prep_kernel<<<16 + acc_blk, 256, 0, stream>>>(pos, p1, jb);
  sa1_kernel<<<16 * 1024 + 16, 256, 0, stream>>>(x, pos, p1, p2, s1w1h, s1w1l,
                                                 s1w2h, s1w2l, s1w3h, s1w3l,
                                                 s1b1, s1b2, s1b3, x1);
  sa2_kernel<<<16 * 256, 256, 0, stream>>>(x1, p1, p2, s2w1h, s2w1l, s2w2h,
                                           s2w2l, s2w3h, s2w3l, s2b1, s2b2,
                                           s2b3, x2);
  gsa_kernel<<<256, 256, 0, stream>>>(x2, p2, g1h, g1l, g2h, g2l, g3h, g3l,
                                      s3b1, s3b2, s3b3, part);
  head1_kernel<<<16, 256, 0, stream>>>(part, l1w, l1b, l2w, l2b, l3w, l3b, hC);
  head2_kernel<<<4, 256, 0, stream>>>(hC, fw1, fb1, fw2, fb2, fw3, fb3, l4w,
                                      l4b, l5w, l5b, out);
}